// Round 8
// baseline (474.151 us; speedup 1.0000x reference)
//
#include <hip/hip_runtime.h>
#include <hip/hip_bf16.h>
#include <cstdint>
#include <cstddef>

#define SCALE_ 0.125f
// B=16 N=256 C=512 H=8 HD=64 E=64

typedef float f4_ __attribute__((ext_vector_type(4)));

__device__ __forceinline__ unsigned pk2(float a, float b) {
  union { __hip_bfloat16 h[2]; unsigned u; } x;
  x.h[0] = __float2bfloat16(a);
  x.h[1] = __float2bfloat16(b);
  return x.u;
}
__device__ __forceinline__ unsigned short bf16b(float a) {
  union { __hip_bfloat16 h; unsigned short s; } x;
  x.h = __float2bfloat16(a);
  return x.s;
}
__device__ __forceinline__ float blo(unsigned u) { return __uint_as_float(u << 16); }
__device__ __forceinline__ float bhi(unsigned u) { return __uint_as_float(u & 0xffff0000u); }

template<int CTRL, int RM>
__device__ __forceinline__ float dppadd(float v) {
  int x = __builtin_amdgcn_update_dpp(0, __float_as_int(v), CTRL, RM, 0xf, true);
  return v + __int_as_float(x);
}
__device__ __forceinline__ float wave_sum64(float v) {
  v = dppadd<0x111, 0xf>(v);   // row_shr:1
  v = dppadd<0x112, 0xf>(v);   // row_shr:2
  v = dppadd<0x114, 0xf>(v);   // row_shr:4
  v = dppadd<0x118, 0xf>(v);   // row_shr:8
  v = dppadd<0x142, 0xa>(v);   // row_bcast:15 -> rows 1,3
  v = dppadd<0x143, 0xc>(v);   // row_bcast:31 -> rows 2,3
  return __int_as_float(__builtin_amdgcn_readlane(__float_as_int(v), 63));
}

// ---------------- Kernel 1: QKV projection GEMM (f32 in, bf16 out) ----------
__global__ __launch_bounds__(256) void qkv_gemm(
    const float* __restrict__ X, const float* __restrict__ W,
    unsigned short* __restrict__ qb, uint2* __restrict__ ktq, uint2* __restrict__ vq)
{
  __shared__ alignas(16) float A_s[16][136];
  __shared__ alignas(16) float W_s[16][72];
  const int t  = threadIdx.x;
  const int m0 = blockIdx.x * 128;
  const int o0 = blockIdx.y * 64;
  const int tm = (t & 15) * 8;
  const int to = (t >> 4) * 4;
  float acc[8][4];
  #pragma unroll
  for (int i = 0; i < 8; i++)
    #pragma unroll
    for (int j = 0; j < 4; j++) acc[i][j] = 0.f;

  const float4* X4 = (const float4*)X;
  const float4* W4 = (const float4*)W;
  for (int c0 = 0; c0 < 512; c0 += 16) {
    #pragma unroll
    for (int i = 0; i < 2; i++) {
      int id = t + 256 * i;
      int row = id >> 2, quad = id & 3;
      float4 a = X4[(size_t)(m0 + row) * 128 + (c0 >> 2) + quad];
      A_s[quad*4+0][row] = a.x; A_s[quad*4+1][row] = a.y;
      A_s[quad*4+2][row] = a.z; A_s[quad*4+3][row] = a.w;
    }
    {
      int row = t >> 2, quad = t & 3;
      float4 w = W4[(size_t)(o0 + row) * 128 + (c0 >> 2) + quad];
      W_s[quad*4+0][row] = w.x; W_s[quad*4+1][row] = w.y;
      W_s[quad*4+2][row] = w.z; W_s[quad*4+3][row] = w.w;
    }
    __syncthreads();
    #pragma unroll
    for (int kk = 0; kk < 16; kk++) {
      float4 a0 = *(const float4*)&A_s[kk][tm];
      float4 a1 = *(const float4*)&A_s[kk][tm + 4];
      float4 w0 = *(const float4*)&W_s[kk][to];
      float am[8] = {a0.x,a0.y,a0.z,a0.w,a1.x,a1.y,a1.z,a1.w};
      float wn[4] = {w0.x,w0.y,w0.z,w0.w};
      #pragma unroll
      for (int i = 0; i < 8; i++)
        #pragma unroll
        for (int j = 0; j < 4; j++) acc[i][j] += am[i] * wn[j];
    }
    __syncthreads();
  }
  const int three = o0 >> 9;
  const int h = (o0 >> 6) & 7;
  if (three == 0) {
    #pragma unroll
    for (int i = 0; i < 8; i++) {
      int m = m0 + tm + i;
      int b = m >> 8, n = m & 255;
      unsigned u0 = pk2(acc[i][0], acc[i][1]);
      unsigned u1 = pk2(acc[i][2], acc[i][3]);
      *(uint2*)&qb[((size_t)(b*8 + h)*256 + n)*64 + to] = make_uint2(u0, u1);
    }
  } else if (three == 1) {
    #pragma unroll
    for (int i = 0; i < 8; i++) {
      int m = m0 + tm + i;
      int b = m >> 8, n = m & 255;
      ktq[(size_t)(b*8 + h)*4096 + (size_t)(to >> 2)*256 + n] =
        make_uint2(pk2(acc[i][0], acc[i][1]), pk2(acc[i][2], acc[i][3]));
    }
  } else {
    int m = m0 + tm;
    int b = m >> 8, n0 = m & 255;
    #pragma unroll
    for (int ii = 0; ii < 2; ii++) {
      #pragma unroll
      for (int j = 0; j < 4; j++) {
        vq[(size_t)(b*8 + h)*4096 + (size_t)((n0 >> 2) + ii)*64 + to + j] =
          make_uint2(pk2(acc[4*ii+0][j], acc[4*ii+1][j]),
                     pk2(acc[4*ii+2][j], acc[4*ii+3][j]));
      }
    }
  }
}

// ======================= SPLIT PATH (ws >= 35 MB) ===========================
// sbt8: bf16 [B][N(x)][N(y)][H] — s_bias (from k_bias), overwritten with t8
//       (attn_sm + residual) by k_attn. uint4 = 8 bf16 per (b,x,y).

// ---- k_bias: s_bias[b,x,y,h] = rb[h] + sum_e edge[b,e,x,y] * rw[h,e] ------
// block = (b, 8 rows); 512 threads: xi = t>>6, yq = t&63 (float4 over y)
__global__ __launch_bounds__(512) void k_bias(
    const float* __restrict__ edge, const float* __restrict__ rw,
    const float* __restrict__ rb, uint4* __restrict__ sbt8)
{
  __shared__ alignas(16) float rw_s[64][8];
  __shared__ float rb_s[8];
  const int t = threadIdx.x;
  const int b = blockIdx.x >> 5;
  const int x0 = (blockIdx.x & 31) * 8;
  rw_s[t >> 3][t & 7] = rw[(t & 7)*64 + (t >> 3)];
  if (t < 8) rb_s[t] = rb[t];
  __syncthreads();

  const int xi = t >> 6, yq = t & 63;
  float acc[8][4];
  #pragma unroll
  for (int h = 0; h < 8; h++) {
    float rv = rb_s[h];
    #pragma unroll
    for (int j = 0; j < 4; j++) acc[h][j] = rv;
  }
  const float4* ep = (const float4*)edge
      + (size_t)b*64*16384 + (size_t)(x0 + xi)*64 + yq;
  #pragma unroll 8
  for (int e = 0; e < 64; e++) {
    float4 v = ep[(size_t)e*16384];
    const float4* rwq = (const float4*)rw_s[e];
    float4 w0 = rwq[0], w1 = rwq[1];
    float wh[8] = {w0.x,w0.y,w0.z,w0.w,w1.x,w1.y,w1.z,w1.w};
    #pragma unroll
    for (int h = 0; h < 8; h++) {
      acc[h][0] += v.x * wh[h];
      acc[h][1] += v.y * wh[h];
      acc[h][2] += v.z * wh[h];
      acc[h][3] += v.w * wh[h];
    }
  }
  #pragma unroll
  for (int j = 0; j < 4; j++) {
    uint4 o;
    o.x = pk2(acc[0][j], acc[1][j]);
    o.y = pk2(acc[2][j], acc[3][j]);
    o.z = pk2(acc[4][j], acc[5][j]);
    o.w = pk2(acc[6][j], acc[7][j]);
    sbt8[(size_t)(b*256 + x0 + xi)*256 + yq*4 + j] = o;
  }
}

// ---- k_attn: QK^T + bias -> exp -> PV (nacc) ; overwrite sbt8 with t8 -----
// block = (b, 8 rows); 1024 threads.
__global__ __launch_bounds__(1024) void k_attn(
    const unsigned short* __restrict__ qb, const uint2* __restrict__ ktq,
    const uint2* __restrict__ vq, uint4* __restrict__ sbt8,
    const unsigned char* __restrict__ mask, unsigned short* __restrict__ naccb)
{
  __shared__ alignas(16) unsigned short p_sb[8][8][264];
  __shared__ alignas(16) float sums_s[8][8];

  const int t = threadIdx.x;
  const int b = blockIdx.x >> 5;
  const int x0 = (blockIdx.x & 31) * 8;
  const int y = t & 255;
  const int xq = t >> 8;

  // phase A: acc = s_bias + scale*QK
  float acc[2][8];
  {
    uint4 s0 = sbt8[(size_t)(b*256 + x0 + 2*xq    )*256 + y];
    uint4 s1 = sbt8[(size_t)(b*256 + x0 + 2*xq + 1)*256 + y];
    acc[0][0]=blo(s0.x); acc[0][1]=bhi(s0.x); acc[0][2]=blo(s0.y); acc[0][3]=bhi(s0.y);
    acc[0][4]=blo(s0.z); acc[0][5]=bhi(s0.z); acc[0][6]=blo(s0.w); acc[0][7]=bhi(s0.w);
    acc[1][0]=blo(s1.x); acc[1][1]=bhi(s1.x); acc[1][2]=blo(s1.y); acc[1][3]=bhi(s1.y);
    acc[1][4]=blo(s1.z); acc[1][5]=bhi(s1.z); acc[1][6]=blo(s1.w); acc[1][7]=bhi(s1.w);
  }
  #pragma unroll 2
  for (int h = 0; h < 8; h++) {
    const uint2* kq = ktq + (size_t)(b*8 + h)*4096 + y;
    const uint4* qA = (const uint4*)(qb + ((size_t)(b*8 + h)*256 + x0 + 2*xq)*64);
    float qk0 = 0.f, qk1 = 0.f;
    #pragma unroll
    for (int d8 = 0; d8 < 8; d8++) {
      uint4 ua = qA[d8], ub = qA[8 + d8];
      uint2 k0 = kq[(size_t)(2*d8)*256];
      uint2 k1 = kq[(size_t)(2*d8+1)*256];
      float kv[8] = {blo(k0.x),bhi(k0.x),blo(k0.y),bhi(k0.y),
                     blo(k1.x),bhi(k1.x),blo(k1.y),bhi(k1.y)};
      float qa[8] = {blo(ua.x),bhi(ua.x),blo(ua.y),bhi(ua.y),
                     blo(ua.z),bhi(ua.z),blo(ua.w),bhi(ua.w)};
      float qbv[8] = {blo(ub.x),bhi(ub.x),blo(ub.y),bhi(ub.y),
                      blo(ub.z),bhi(ub.z),blo(ub.w),bhi(ub.w)};
      #pragma unroll
      for (int j = 0; j < 8; j++) { qk0 += qa[j]*kv[j]; qk1 += qbv[j]*kv[j]; }
    }
    acc[0][h] += SCALE_ * qk0;
    acc[1][h] += SCALE_ * qk1;
  }

  const float madd0 = mask[(size_t)b*65536 + (size_t)(x0 + 2*xq)*256 + y] ? -1e30f : 0.f;
  const float madd1 = mask[(size_t)b*65536 + (size_t)(x0 + 2*xq)*256 + 256 + y] ? -1e30f : 0.f;
  #pragma unroll
  for (int h = 0; h < 8; h++) {
    p_sb[2*xq    ][h][y] = bf16b(__expf(acc[0][h] + madd0));
    p_sb[2*xq + 1][h][y] = bf16b(__expf(acc[1][h] + madd1));
  }
  __syncthreads();

  // PV: thread -> (x4, h4, 4 d's); write nacc (bf16) direct to global
  {
    const int x4 = t >> 7;
    const int h4 = (t >> 4) & 7;
    const int d4 = t & 15;
    const uint2* vp = vq + (size_t)(b*8 + h4)*4096 + d4*4;
    float a4[4] = {0.f, 0.f, 0.f, 0.f};
    float psum = 0.f;
    #pragma unroll 4
    for (int y4 = 0; y4 < 64; y4++) {
      uint2 pv_ = *(const uint2*)&p_sb[x4][h4][y4*4];
      float pj0 = blo(pv_.x), pj1 = bhi(pv_.x), pj2 = blo(pv_.y), pj3 = bhi(pv_.y);
      psum += (pj0 + pj1) + (pj2 + pj3);
      #pragma unroll
      for (int j = 0; j < 4; j++) {
        uint2 uv = vp[(size_t)y4*64 + j];
        float v0 = blo(uv.x), v1 = bhi(uv.x), v2 = blo(uv.y), v3 = bhi(uv.y);
        a4[j] += pj0*v0 + pj1*v1 + pj2*v2 + pj3*v3;
      }
    }
    float inv = 1.0f / psum;
    *(uint2*)&naccb[(size_t)(b*256 + x0 + x4)*512 + h4*64 + d4*4] =
      make_uint2(pk2(a4[0]*inv, a4[1]*inv), pk2(a4[2]*inv, a4[3]*inv));
    if (d4 == 0) sums_s[x4][h4] = psum;
  }
  __syncthreads();

  // t8 = attn_sm + residual -> overwrite sbt8 (this block's region only)
  #pragma unroll
  for (int r = 0; r < 2; r++) {
    float madd = r ? madd1 : madd0;
    float v[8];
    #pragma unroll
    for (int h = 0; h < 8; h++) {
      float inv = 1.0f / sums_s[2*xq + r][h];
      float pe = __expf(acc[r][h] + madd);
      v[h] = pe*inv + acc[r][h];
    }
    uint4 o;
    o.x = pk2(v[0], v[1]); o.y = pk2(v[2], v[3]);
    o.z = pk2(v[4], v[5]); o.w = pk2(v[6], v[7]);
    sbt8[(size_t)(b*256 + x0 + 2*xq + r)*256 + y] = o;
  }
}

// ---- k_edge: edge_out = t8 @ ew + eb ; pooled softmax -> pl ---------------
// block = (b, 8 rows); 512 threads = 8 waves; wave = one x-row; barrier-free.
__global__ __launch_bounds__(512) void k_edge(
    const uint4* __restrict__ sbt8, const unsigned char* __restrict__ mask,
    const float* __restrict__ ew, const float* __restrict__ eb,
    float* __restrict__ out_edge, float* __restrict__ pl)
{
  __shared__ alignas(16) float ew_s[64][8];
  __shared__ alignas(16) float eb_s[64];
  const int t = threadIdx.x;
  const int b = blockIdx.x >> 5;
  const int x0 = (blockIdx.x & 31) * 8;
  ((float*)ew_s)[t] = ew[t];
  if (t < 64) eb_s[t] = eb[t];
  __syncthreads();

  const int xi = t >> 6, lane = t & 63;
  const int y0 = lane * 4;
  const int xg = x0 + xi;

  float tf[4][8];
  #pragma unroll
  for (int j = 0; j < 4; j++) {
    uint4 u = sbt8[(size_t)(b*256 + xg)*256 + y0 + j];
    tf[j][0]=blo(u.x); tf[j][1]=bhi(u.x); tf[j][2]=blo(u.y); tf[j][3]=bhi(u.y);
    tf[j][4]=blo(u.z); tf[j][5]=bhi(u.z); tf[j][6]=blo(u.w); tf[j][7]=bhi(u.w);
  }
  uchar4 mb = *(const uchar4*)&mask[(size_t)b*65536 + (size_t)xg*256 + y0];
  const float md[4] = {mb.x ? -1e30f : 0.f, mb.y ? -1e30f : 0.f,
                       mb.z ? -1e30f : 0.f, mb.w ? -1e30f : 0.f};

  for (int e = 0; e < 64; e++) {
    const float4* ewq = (const float4*)ew_s[e];
    float4 w0 = ewq[0], w1 = ewq[1];
    float wh[8] = {w0.x,w0.y,w0.z,w0.w,w1.x,w1.y,w1.z,w1.w};
    float ebv = eb_s[e];
    float eo[4];
    #pragma unroll
    for (int j = 0; j < 4; j++) {
      float s = ebv;
      #pragma unroll
      for (int h = 0; h < 8; h++) s += tf[j][h]*wh[h];
      eo[j] = s;
    }
    float e0 = __expf(eo[0]+md[0]), e1 = __expf(eo[1]+md[1]);
    float e2 = __expf(eo[2]+md[2]), e3 = __expf(eo[3]+md[3]);
    float se  = (e0 + e1) + (e2 + e3);
    float swe = (e0*eo[0] + e1*eo[1]) + (e2*eo[2] + e3*eo[3]);
    se  = wave_sum64(se);
    swe = wave_sum64(swe);
    if (lane == 0) pl[(size_t)(b*256 + xg)*64 + e] = swe / se;
    f4_ ov = {eo[0], eo[1], eo[2], eo[3]};
    __builtin_nontemporal_store(ov,
      (f4_*)&out_edge[((size_t)(b*64 + e)*256 + xg)*256 + y0]);
  }
}

// ---- k_fc: naccb[m][c] += fcb[c] + pl[m] . fcw[c]  (in place, bf16) -------
__global__ __launch_bounds__(256) void k_fc(
    unsigned short* __restrict__ naccb, const float* __restrict__ pl,
    const float* __restrict__ fcw, const float* __restrict__ fcb)
{
  __shared__ alignas(16) float pl_s[2][64];
  const int t = threadIdx.x;
  const int m0 = blockIdx.x * 2;
  if (t < 128) pl_s[t >> 6][t & 63] = pl[(size_t)(m0 + (t >> 6))*64 + (t & 63)];
  __syncthreads();
  const int mi = t >> 7;
  const int c4 = (t & 127) * 4;
  const size_t m = m0 + mi;
  uint2 u = *(const uint2*)&naccb[m*512 + c4];
  float a[4] = {blo(u.x), bhi(u.x), blo(u.y), bhi(u.y)};
  #pragma unroll
  for (int j = 0; j < 4; j++) a[j] += fcb[c4 + j];
  const float4* fw4 = (const float4*)fcw;
  #pragma unroll 4
  for (int e4 = 0; e4 < 16; e4++) {
    float4 p4 = *(const float4*)&pl_s[mi][e4*4];
    #pragma unroll
    for (int j = 0; j < 4; j++) {
      float4 f = fw4[(size_t)(c4 + j)*16 + e4];
      a[j] += p4.x*f.x + p4.y*f.y + p4.z*f.z + p4.w*f.w;
    }
  }
  *(uint2*)&naccb[m*512 + c4] = make_uint2(pk2(a[0], a[1]), pk2(a[2], a[3]));
}

// ================= FALLBACK PATH (round-7 fused kernel) =====================
__global__ __launch_bounds__(1024) void fused_attn(
    const unsigned short* __restrict__ qb, const uint2* __restrict__ ktq,
    const uint2* __restrict__ vq,
    const float* __restrict__ edge, const unsigned char* __restrict__ mask,
    const float* __restrict__ rw, const float* __restrict__ rb,
    const float* __restrict__ ew, const float* __restrict__ eb,
    const float* __restrict__ fcw, const float* __restrict__ fcb,
    float* __restrict__ out_edge, unsigned short* __restrict__ tmpb)
{
  __shared__ alignas(16) unsigned short p_sb[8][8][264];
  __shared__ alignas(16) float nacc_s[8][512];
  __shared__ alignas(16) float rw_s[64][8];
  __shared__ alignas(16) float ew_s[64][8];
  __shared__ alignas(16) float eb_s[64];
  __shared__ alignas(16) unsigned char mkb[8][256];
  __shared__ alignas(16) float sums_s[8][8];
  __shared__ alignas(16) float pl_s[8][64];

  const int t = threadIdx.x;
  const int lane = t & 63;
  const int wv = t >> 6;
  const int b = blockIdx.x >> 5;
  const int x0 = (blockIdx.x & 31) * 8;

  if (t < 512) rw_s[t >> 3][t & 7] = rw[(t & 7)*64 + (t >> 3)];
  if (t < 512) ((float*)ew_s)[t] = ew[t];
  if (t < 64) eb_s[t] = eb[t];
  if (t < 512)
    ((unsigned*)mkb)[t] =
      ((const unsigned*)(mask + (size_t)b*65536 + (size_t)x0*256))[t];
  __syncthreads();

  const int y = t & 255;
  const int xq = t >> 8;

  float acc[2][8];
  #pragma unroll
  for (int h = 0; h < 8; h++) { float rv = rb[h]; acc[0][h] = rv; acc[1][h] = rv; }
  {
    const float* ep = edge + (size_t)b*4194304 + (size_t)(x0 + 2*xq)*256 + y;
    #pragma unroll 4
    for (int e = 0; e < 64; e++) {
      float v0 = ep[(size_t)e*65536];
      float v1 = ep[(size_t)e*65536 + 256];
      const float4* rwq = (const float4*)rw_s[e];
      float4 w0 = rwq[0], w1 = rwq[1];
      float wh[8] = {w0.x,w0.y,w0.z,w0.w,w1.x,w1.y,w1.z,w1.w};
      #pragma unroll
      for (int h = 0; h < 8; h++) {
        acc[0][h] += v0 * wh[h];
        acc[1][h] += v1 * wh[h];
      }
    }
  }
  #pragma unroll 2
  for (int h = 0; h < 8; h++) {
    const uint2* kq = ktq + (size_t)(b*8 + h)*4096 + y;
    const uint4* qA = (const uint4*)(qb + ((size_t)(b*8 + h)*256 + x0 + 2*xq)*64);
    float qk0 = 0.f, qk1 = 0.f;
    #pragma unroll
    for (int d8 = 0; d8 < 8; d8++) {
      uint4 ua = qA[d8], ub = qA[8 + d8];
      uint2 k0 = kq[(size_t)(2*d8)*256];
      uint2 k1 = kq[(size_t)(2*d8+1)*256];
      float kv[8] = {blo(k0.x),bhi(k0.x),blo(k0.y),bhi(k0.y),
                     blo(k1.x),bhi(k1.x),blo(k1.y),bhi(k1.y)};
      float qa[8] = {blo(ua.x),bhi(ua.x),blo(ua.y),bhi(ua.y),
                     blo(ua.z),bhi(ua.z),blo(ua.w),bhi(ua.w)};
      float qbv[8] = {blo(ub.x),bhi(ub.x),blo(ub.y),bhi(ub.y),
                      blo(ub.z),bhi(ub.z),blo(ub.w),bhi(ub.w)};
      #pragma unroll
      for (int j = 0; j < 8; j++) { qk0 += qa[j]*kv[j]; qk1 += qbv[j]*kv[j]; }
    }
    acc[0][h] += SCALE_ * qk0;
    acc[1][h] += SCALE_ * qk1;
  }

  const float madd0 = mkb[2*xq][y]     ? -1e30f : 0.f;
  const float madd1 = mkb[2*xq + 1][y] ? -1e30f : 0.f;
  #pragma unroll
  for (int h = 0; h < 8; h++) {
    p_sb[2*xq    ][h][y] = bf16b(__expf(acc[0][h] + madd0));
    p_sb[2*xq + 1][h][y] = bf16b(__expf(acc[1][h] + madd1));
  }
  __syncthreads();

  {
    const int x4 = t >> 7;
    const int h4 = (t >> 4) & 7;
    const int d4 = t & 15;
    const uint2* vp = vq + (size_t)(b*8 + h4)*4096 + d4*4;
    float a4[4] = {0.f, 0.f, 0.f, 0.f};
    float psum = 0.f;
    #pragma unroll 4
    for (int y4 = 0; y4 < 64; y4++) {
      uint2 pv_ = *(const uint2*)&p_sb[x4][h4][y4*4];
      float pj0 = blo(pv_.x), pj1 = bhi(pv_.x), pj2 = blo(pv_.y), pj3 = bhi(pv_.y);
      psum += (pj0 + pj1) + (pj2 + pj3);
      #pragma unroll
      for (int j = 0; j < 4; j++) {
        uint2 uv = vp[(size_t)y4*64 + j];
        float v0 = blo(uv.x), v1 = bhi(uv.x), v2 = blo(uv.y), v3 = bhi(uv.y);
        a4[j] += pj0*v0 + pj1*v1 + pj2*v2 + pj3*v3;
      }
    }
    float inv = 1.0f / psum;
    float4 o;
    o.x = a4[0]*inv; o.y = a4[1]*inv; o.z = a4[2]*inv; o.w = a4[3]*inv;
    *(float4*)&nacc_s[x4][h4*64 + d4*4] = o;
    if (d4 == 0) sums_s[x4][h4] = psum;
  }
  __syncthreads();

  #pragma unroll
  for (int r = 0; r < 2; r++) {
    float madd = r ? madd1 : madd0;
    #pragma unroll
    for (int h = 0; h < 8; h++) {
      float inv = 1.0f / sums_s[2*xq + r][h];
      float pe = __expf(acc[r][h] + madd);
      p_sb[2*xq + r][h][y] = bf16b(pe*inv + acc[r][h]);
    }
  }
  __syncthreads();

  {
    const int xi5 = wv & 7;
    const int epar = wv >> 3;
    const int y0 = lane * 4;
    const int xg = x0 + xi5;
    uchar4 mb = *(const uchar4*)&mkb[xi5][y0];
    const float md0 = mb.x ? -1e30f : 0.f;
    const float md1 = mb.y ? -1e30f : 0.f;
    const float md2 = mb.z ? -1e30f : 0.f;
    const float md3 = mb.w ? -1e30f : 0.f;
    uint2 tvh[8];
    #pragma unroll
    for (int h = 0; h < 8; h++) tvh[h] = *(const uint2*)&p_sb[xi5][h][y0];
    const float4* ew4 = (const float4*)ew_s;
    for (int ec = 0; ec < 32; ec++) {
      int e = ec*2 + epar;
      float4 w0 = ew4[e*2], w1 = ew4[e*2+1];
      float wh[8] = {w0.x,w0.y,w0.z,w0.w,w1.x,w1.y,w1.z,w1.w};
      float ebv = eb_s[e];
      float eo0 = ebv, eo1 = ebv, eo2 = ebv, eo3 = ebv;
      #pragma unroll
      for (int h = 0; h < 8; h++) {
        uint2 tv = tvh[h];
        eo0 += blo(tv.x)*wh[h];
        eo1 += bhi(tv.x)*wh[h];
        eo2 += blo(tv.y)*wh[h];
        eo3 += bhi(tv.y)*wh[h];
      }
      float e0 = __expf(eo0+md0), e1 = __expf(eo1+md1);
      float e2 = __expf(eo2+md2), e3 = __expf(eo3+md3);
      float se  = (e0 + e1) + (e2 + e3);
      float swe = (e0*eo0 + e1*eo1) + (e2*eo2 + e3*eo3);
      se  = wave_sum64(se);
      swe = wave_sum64(swe);
      if (lane == 0) pl_s[xi5][e] = swe / se;
      f4_ ov = {eo0, eo1, eo2, eo3};
      __builtin_nontemporal_store(ov,
        (f4_*)&out_edge[((size_t)(b*64 + e)*256 + xg)*256 + y0]);
    }
  }
  __syncthreads();

  {
    const int xi6 = t >> 7;
    const int c4 = (t & 127) * 4;
    const int xg = x0 + xi6;
    float4 a = *(const float4*)&nacc_s[xi6][c4];
    float4 bias = *(const float4*)&fcb[c4];
    a.x += bias.x; a.y += bias.y; a.z += bias.z; a.w += bias.w;
    const float4* fw4 = (const float4*)fcw;
    #pragma unroll 4
    for (int e4 = 0; e4 < 16; e4++) {
      float4 pl4 = *(const float4*)&pl_s[xi6][e4*4];
      float4 f0 = fw4[(size_t)(c4+0)*16 + e4];
      float4 f1 = fw4[(size_t)(c4+1)*16 + e4];
      float4 f2 = fw4[(size_t)(c4+2)*16 + e4];
      float4 f3 = fw4[(size_t)(c4+3)*16 + e4];
      a.x += pl4.x*f0.x + pl4.y*f0.y + pl4.z*f0.z + pl4.w*f0.w;
      a.y += pl4.x*f1.x + pl4.y*f1.y + pl4.z*f1.z + pl4.w*f1.w;
      a.z += pl4.x*f2.x + pl4.y*f2.y + pl4.z*f2.z + pl4.w*f2.w;
      a.w += pl4.x*f3.x + pl4.y*f3.y + pl4.z*f3.z + pl4.w*f3.w;
    }
    *(uint2*)&tmpb[((size_t)b*256 + xg)*512 + c4] =
      make_uint2(pk2(a.x, a.y), pk2(a.z, a.w));
  }
}

// ---------------- Output projection GEMM + bias (bf16 in) -------------------
__global__ __launch_bounds__(256) void proj_gemm(
    const unsigned short* __restrict__ Xb, const float* __restrict__ W,
    const float* __restrict__ bias, float* __restrict__ out)
{
  __shared__ alignas(16) float A_s[16][136];
  __shared__ alignas(16) float W_s[16][72];
  const int t  = threadIdx.x;
  const int m0 = blockIdx.x * 128;
  const int o0 = blockIdx.y * 64;
  const int tm = (t & 15) * 8;
  const int to = (t >> 4) * 4;
  float acc[8][4];
  #pragma unroll
  for (int i = 0; i < 8; i++)
    #pragma unroll
    for (int j = 0; j < 4; j++) acc[i][j] = 0.f;

  const uint4* X4 = (const uint4*)Xb;
  const float4* W4 = (const float4*)W;
  for (int c0 = 0; c0 < 512; c0 += 16) {
    {
      int row = t >> 1, half = t & 1;
      uint4 a = X4[(size_t)(m0 + row) * 64 + (c0 >> 3) + half];
      int cb = half*8;
      A_s[cb+0][row] = blo(a.x); A_s[cb+1][row] = bhi(a.x);
      A_s[cb+2][row] = blo(a.y); A_s[cb+3][row] = bhi(a.y);
      A_s[cb+4][row] = blo(a.z); A_s[cb+5][row] = bhi(a.z);
      A_s[cb+6][row] = blo(a.w); A_s[cb+7][row] = bhi(a.w);
    }
    {
      int row = t >> 2, quad = t & 3;
      float4 w = W4[(size_t)(o0 + row) * 128 + (c0 >> 2) + quad];
      W_s[quad*4+0][row] = w.x; W_s[quad*4+1][row] = w.y;
      W_s[quad*4+2][row] = w.z; W_s[quad*4+3][row] = w.w;
    }
    __syncthreads();
    #pragma unroll
    for (int kk = 0; kk < 16; kk++) {
      float4 a0 = *(const float4*)&A_s[kk][tm];
      float4 a1 = *(const float4*)&A_s[kk][tm + 4];
      float4 w0 = *(const float4*)&W_s[kk][to];
      float am[8] = {a0.x,a0.y,a0.z,a0.w,a1.x,a1.y,a1.z,a1.w};
      float wn[4] = {w0.x,w0.y,w0.z,w0.w};
      #pragma unroll
      for (int i = 0; i < 8; i++)
        #pragma unroll
        for (int j = 0; j < 4; j++) acc[i][j] += am[i] * wn[j];
    }
    __syncthreads();
  }
  float4 bb = *(const float4*)&bias[o0 + to];
  #pragma unroll
  for (int i = 0; i < 8; i++) {
    int m = m0 + tm + i;
    float4 r = make_float4(acc[i][0]+bb.x, acc[i][1]+bb.y, acc[i][2]+bb.z, acc[i][3]+bb.w);
    *(float4*)&out[(size_t)m*512 + o0 + to] = r;
  }
}

extern "C" void kernel_launch(void* const* d_in, const int* in_sizes, int n_in,
                              void* d_out, int out_size, void* d_ws, size_t ws_size,
                              hipStream_t stream)
{
  (void)in_sizes; (void)n_in; (void)out_size;
  const float* node   = (const float*)d_in[0];
  const float* edge   = (const float*)d_in[1];
  const unsigned char* mask = (const unsigned char*)d_in[2];
  const float* qkv_w  = (const float*)d_in[3];
  const float* proj_w = (const float*)d_in[4];
  const float* proj_b = (const float*)d_in[5];
  const float* rw     = (const float*)d_in[6];
  const float* rb     = (const float*)d_in[7];
  const float* ew     = (const float*)d_in[8];
  const float* eb     = (const float*)d_in[9];
  const float* fcw    = (const float*)d_in[10];
  const float* fcb    = (const float*)d_in[11];

  float* out_node = (float*)d_out;
  float* out_edge = out_node + (size_t)16*256*512;

  char* ws = (char*)d_ws;
  unsigned short* qb  = (unsigned short*)(ws);                    // 4 MB
  uint2*          ktq = (uint2*)         (ws + (size_t)4*1024*1024);
  uint2*          vq  = (uint2*)         (ws + (size_t)8*1024*1024);

  if (ws_size >= 35u*1024*1024) {
    // split path: sbt8 16.8 MB @12M, nacc/tmp 4 MB @~28M, pl 1 MB after
    uint4*          sbt8  = (uint4*)         (ws + (size_t)12*1024*1024);
    unsigned short* naccb = (unsigned short*)(ws + (size_t)12*1024*1024 + 16777216);
    float*          pl    = (float*)         (ws + (size_t)12*1024*1024 + 16777216 + 4194304);

    qkv_gemm <<<dim3(32, 24, 1), 256, 0, stream>>>(node, qkv_w, qb, ktq, vq);
    k_bias   <<<512,  512, 0, stream>>>(edge, rw, rb, sbt8);
    k_attn   <<<512, 1024, 0, stream>>>(qb, ktq, vq, sbt8, mask, naccb);
    k_edge   <<<512,  512, 0, stream>>>(sbt8, mask, ew, eb, out_edge, pl);
    k_fc     <<<2048, 256, 0, stream>>>(naccb, pl, fcw, fcb);
    proj_gemm<<<dim3(32, 8, 1), 256, 0, stream>>>(naccb, proj_w, proj_b, out_node);
  } else {
    // fallback: round-7 fused path (16 MB workspace)
    unsigned short* tmpb = (unsigned short*)(ws + (size_t)12*1024*1024);
    qkv_gemm <<<dim3(32, 24, 1), 256, 0, stream>>>(node, qkv_w, qb, ktq, vq);
    fused_attn<<<dim3(512, 1, 1), 1024, 0, stream>>>(qb, ktq, vq, edge, mask,
                                                     rw, rb, ew, eb, fcw, fcb,
                                                     out_edge, tmpb);
    proj_gemm<<<dim3(32, 8, 1), 256, 0, stream>>>(tmpb, proj_w, proj_b, out_node);
  }
}

// Round 9
// 450.424 us; speedup vs baseline: 1.0527x; 1.0527x over previous
//
#include <hip/hip_runtime.h>
#include <hip/hip_bf16.h>
#include <cstdint>
#include <cstddef>

#define SCALE_ 0.125f
// B=16 N=256 C=512 H=8 HD=64 E=64

typedef float f4_ __attribute__((ext_vector_type(4)));

__device__ __forceinline__ unsigned pk2(float a, float b) {
  union { __hip_bfloat16 h[2]; unsigned u; } x;
  x.h[0] = __float2bfloat16(a);
  x.h[1] = __float2bfloat16(b);
  return x.u;
}
__device__ __forceinline__ unsigned short bf16b(float a) {
  union { __hip_bfloat16 h; unsigned short s; } x;
  x.h = __float2bfloat16(a);
  return x.s;
}
__device__ __forceinline__ float blo(unsigned u) { return __uint_as_float(u << 16); }
__device__ __forceinline__ float bhi(unsigned u) { return __uint_as_float(u & 0xffff0000u); }

template<int CTRL, int RM>
__device__ __forceinline__ float dppadd(float v) {
  int x = __builtin_amdgcn_update_dpp(0, __float_as_int(v), CTRL, RM, 0xf, true);
  return v + __int_as_float(x);
}
__device__ __forceinline__ float wave_sum64(float v) {
  v = dppadd<0x111, 0xf>(v);   // row_shr:1
  v = dppadd<0x112, 0xf>(v);   // row_shr:2
  v = dppadd<0x114, 0xf>(v);   // row_shr:4
  v = dppadd<0x118, 0xf>(v);   // row_shr:8
  v = dppadd<0x142, 0xa>(v);   // row_bcast:15 -> rows 1,3
  v = dppadd<0x143, 0xc>(v);   // row_bcast:31 -> rows 2,3
  return __int_as_float(__builtin_amdgcn_readlane(__float_as_int(v), 63));
}

// ---------------- Kernel 1: QKV projection GEMM (f32 in, bf16 out) ----------
__global__ __launch_bounds__(256) void qkv_gemm(
    const float* __restrict__ X, const float* __restrict__ W,
    unsigned short* __restrict__ qb, uint2* __restrict__ ktq, uint2* __restrict__ vq)
{
  __shared__ alignas(16) float A_s[16][136];
  __shared__ alignas(16) float W_s[16][72];
  const int t  = threadIdx.x;
  const int m0 = blockIdx.x * 128;
  const int o0 = blockIdx.y * 64;
  const int tm = (t & 15) * 8;
  const int to = (t >> 4) * 4;
  float acc[8][4];
  #pragma unroll
  for (int i = 0; i < 8; i++)
    #pragma unroll
    for (int j = 0; j < 4; j++) acc[i][j] = 0.f;

  const float4* X4 = (const float4*)X;
  const float4* W4 = (const float4*)W;
  for (int c0 = 0; c0 < 512; c0 += 16) {
    #pragma unroll
    for (int i = 0; i < 2; i++) {
      int id = t + 256 * i;
      int row = id >> 2, quad = id & 3;
      float4 a = X4[(size_t)(m0 + row) * 128 + (c0 >> 2) + quad];
      A_s[quad*4+0][row] = a.x; A_s[quad*4+1][row] = a.y;
      A_s[quad*4+2][row] = a.z; A_s[quad*4+3][row] = a.w;
    }
    {
      int row = t >> 2, quad = t & 3;
      float4 w = W4[(size_t)(o0 + row) * 128 + (c0 >> 2) + quad];
      W_s[quad*4+0][row] = w.x; W_s[quad*4+1][row] = w.y;
      W_s[quad*4+2][row] = w.z; W_s[quad*4+3][row] = w.w;
    }
    __syncthreads();
    #pragma unroll
    for (int kk = 0; kk < 16; kk++) {
      float4 a0 = *(const float4*)&A_s[kk][tm];
      float4 a1 = *(const float4*)&A_s[kk][tm + 4];
      float4 w0 = *(const float4*)&W_s[kk][to];
      float am[8] = {a0.x,a0.y,a0.z,a0.w,a1.x,a1.y,a1.z,a1.w};
      float wn[4] = {w0.x,w0.y,w0.z,w0.w};
      #pragma unroll
      for (int i = 0; i < 8; i++)
        #pragma unroll
        for (int j = 0; j < 4; j++) acc[i][j] += am[i] * wn[j];
    }
    __syncthreads();
  }
  const int three = o0 >> 9;
  const int h = (o0 >> 6) & 7;
  if (three == 0) {
    #pragma unroll
    for (int i = 0; i < 8; i++) {
      int m = m0 + tm + i;
      int b = m >> 8, n = m & 255;
      unsigned u0 = pk2(acc[i][0], acc[i][1]);
      unsigned u1 = pk2(acc[i][2], acc[i][3]);
      *(uint2*)&qb[((size_t)(b*8 + h)*256 + n)*64 + to] = make_uint2(u0, u1);
    }
  } else if (three == 1) {
    #pragma unroll
    for (int i = 0; i < 8; i++) {
      int m = m0 + tm + i;
      int b = m >> 8, n = m & 255;
      ktq[(size_t)(b*8 + h)*4096 + (size_t)(to >> 2)*256 + n] =
        make_uint2(pk2(acc[i][0], acc[i][1]), pk2(acc[i][2], acc[i][3]));
    }
  } else {
    int m = m0 + tm;
    int b = m >> 8, n0 = m & 255;
    #pragma unroll
    for (int ii = 0; ii < 2; ii++) {
      #pragma unroll
      for (int j = 0; j < 4; j++) {
        vq[(size_t)(b*8 + h)*4096 + (size_t)((n0 >> 2) + ii)*64 + to + j] =
          make_uint2(pk2(acc[4*ii+0][j], acc[4*ii+1][j]),
                     pk2(acc[4*ii+2][j], acc[4*ii+3][j]));
      }
    }
  }
}

// ---- k_bias: s_bias[b,x,y,h] = rb[h] + sum_e edge[b,e,x,y]*rw[h,e] ---------
// 256 threads: xi = t>>6 (4 rows), yq = t&63 (float4 over y). grid 1024.
__global__ __launch_bounds__(256) void k_bias(
    const float* __restrict__ edge, const float* __restrict__ rw,
    const float* __restrict__ rb, uint4* __restrict__ sbt8)
{
  __shared__ alignas(16) float rw_s[64][8];
  __shared__ float rb_s[8];
  const int t = threadIdx.x;
  const int b = blockIdx.x >> 6;
  const int x0 = (blockIdx.x & 63) * 4;
  for (int i = t; i < 512; i += 256) rw_s[i >> 3][i & 7] = rw[(i & 7)*64 + (i >> 3)];
  if (t < 8) rb_s[t] = rb[t];
  __syncthreads();

  const int xi = t >> 6, yq = t & 63;
  float acc[8][4];
  #pragma unroll
  for (int h = 0; h < 8; h++) {
    float rv = rb_s[h];
    #pragma unroll
    for (int j = 0; j < 4; j++) acc[h][j] = rv;
  }
  const f4_* ep = (const f4_*)edge + (size_t)b*64*16384 + (size_t)(x0 + xi)*64 + yq;
  #pragma unroll 4
  for (int e = 0; e < 64; e++) {
    f4_ v = __builtin_nontemporal_load(ep + (size_t)e*16384);
    const float4* rwq = (const float4*)rw_s[e];
    float4 w0 = rwq[0], w1 = rwq[1];
    float wh[8] = {w0.x,w0.y,w0.z,w0.w,w1.x,w1.y,w1.z,w1.w};
    #pragma unroll
    for (int h = 0; h < 8; h++) {
      acc[h][0] += v.x * wh[h];
      acc[h][1] += v.y * wh[h];
      acc[h][2] += v.z * wh[h];
      acc[h][3] += v.w * wh[h];
    }
  }
  #pragma unroll
  for (int j = 0; j < 4; j++) {
    uint4 o;
    o.x = pk2(acc[0][j], acc[1][j]);
    o.y = pk2(acc[2][j], acc[3][j]);
    o.z = pk2(acc[4][j], acc[5][j]);
    o.w = pk2(acc[6][j], acc[7][j]);
    sbt8[(size_t)(b*256 + x0 + xi)*256 + yq*4 + j] = o;
  }
}

// ---- k_attn: 2 rows/block, 256 threads, grid 2048. --------------------------
// QK^T + bias -> exp -> p_sb (8.5 KB) -> PV (+psum) -> nacc; t8 -> sbt8.
__global__ __launch_bounds__(256) void k_attn(
    const unsigned short* __restrict__ qb, const uint2* __restrict__ ktq,
    const uint2* __restrict__ vq, uint4* __restrict__ sbt8,
    const unsigned char* __restrict__ mask, unsigned short* __restrict__ naccb)
{
  __shared__ alignas(16) unsigned short p_sb[2][8][264];
  __shared__ alignas(16) float sums_s[2][8];

  const int t = threadIdx.x;
  const int b = blockIdx.x >> 7;
  const int x0 = (blockIdx.x & 127) * 2;
  const int y = t;

  // scores = s_bias + scale*QK
  float acc[2][8];
  {
    uint4 s0 = sbt8[(size_t)(b*256 + x0    )*256 + y];
    uint4 s1 = sbt8[(size_t)(b*256 + x0 + 1)*256 + y];
    acc[0][0]=blo(s0.x); acc[0][1]=bhi(s0.x); acc[0][2]=blo(s0.y); acc[0][3]=bhi(s0.y);
    acc[0][4]=blo(s0.z); acc[0][5]=bhi(s0.z); acc[0][6]=blo(s0.w); acc[0][7]=bhi(s0.w);
    acc[1][0]=blo(s1.x); acc[1][1]=bhi(s1.x); acc[1][2]=blo(s1.y); acc[1][3]=bhi(s1.y);
    acc[1][4]=blo(s1.z); acc[1][5]=bhi(s1.z); acc[1][6]=blo(s1.w); acc[1][7]=bhi(s1.w);
  }
  #pragma unroll 2
  for (int h = 0; h < 8; h++) {
    const uint2* kq = ktq + (size_t)(b*8 + h)*4096 + y;
    const uint4* qA = (const uint4*)(qb + ((size_t)(b*8 + h)*256 + x0)*64);
    float qk0 = 0.f, qk1 = 0.f;
    #pragma unroll
    for (int d8 = 0; d8 < 8; d8++) {
      uint4 ua = qA[d8], ub = qA[8 + d8];           // rows x0, x0+1
      uint2 k0 = kq[(size_t)(2*d8)*256];
      uint2 k1 = kq[(size_t)(2*d8+1)*256];
      float kv[8] = {blo(k0.x),bhi(k0.x),blo(k0.y),bhi(k0.y),
                     blo(k1.x),bhi(k1.x),blo(k1.y),bhi(k1.y)};
      float qa[8] = {blo(ua.x),bhi(ua.x),blo(ua.y),bhi(ua.y),
                     blo(ua.z),bhi(ua.z),blo(ua.w),bhi(ua.w)};
      float qbv[8] = {blo(ub.x),bhi(ub.x),blo(ub.y),bhi(ub.y),
                      blo(ub.z),bhi(ub.z),blo(ub.w),bhi(ub.w)};
      #pragma unroll
      for (int j = 0; j < 8; j++) { qk0 += qa[j]*kv[j]; qk1 += qbv[j]*kv[j]; }
    }
    acc[0][h] += SCALE_ * qk0;
    acc[1][h] += SCALE_ * qk1;
  }

  const float madd0 = mask[(size_t)b*65536 + (size_t)x0*256 + y]       ? -1e30f : 0.f;
  const float madd1 = mask[(size_t)b*65536 + (size_t)x0*256 + 256 + y] ? -1e30f : 0.f;
  #pragma unroll
  for (int h = 0; h < 8; h++) {
    p_sb[0][h][y] = bf16b(__expf(acc[0][h] + madd0));
    p_sb[1][h][y] = bf16b(__expf(acc[1][h] + madd1));
  }
  __syncthreads();

  // PV: thread -> (h = t>>5, d0 = (t&31)*2); psum redundantly per h.
  {
    const int h = t >> 5;
    const int d0 = (t & 31) * 2;
    const uint2* vp = vq + (size_t)(b*8 + h)*4096;
    float a00 = 0.f, a01 = 0.f, a10 = 0.f, a11 = 0.f;
    float ps0 = 0.f, ps1 = 0.f;
    #pragma unroll 4
    for (int y4 = 0; y4 < 64; y4++) {
      uint2 p0 = *(const uint2*)&p_sb[0][h][y4*4];
      uint2 p1 = *(const uint2*)&p_sb[1][h][y4*4];
      float pj0 = blo(p0.x), pj1 = bhi(p0.x), pj2 = blo(p0.y), pj3 = bhi(p0.y);
      float qj0 = blo(p1.x), qj1 = bhi(p1.x), qj2 = blo(p1.y), qj3 = bhi(p1.y);
      ps0 += (pj0 + pj1) + (pj2 + pj3);
      ps1 += (qj0 + qj1) + (qj2 + qj3);
      uint2 v0 = vp[(size_t)y4*64 + d0];
      uint2 v1 = vp[(size_t)y4*64 + d0 + 1];
      float va0 = blo(v0.x), va1 = bhi(v0.x), va2 = blo(v0.y), va3 = bhi(v0.y);
      float vb0 = blo(v1.x), vb1 = bhi(v1.x), vb2 = blo(v1.y), vb3 = bhi(v1.y);
      a00 += pj0*va0 + pj1*va1 + pj2*va2 + pj3*va3;
      a01 += pj0*vb0 + pj1*vb1 + pj2*vb2 + pj3*vb3;
      a10 += qj0*va0 + qj1*va1 + qj2*va2 + qj3*va3;
      a11 += qj0*vb0 + qj1*vb1 + qj2*vb2 + qj3*vb3;
    }
    float inv0 = 1.0f / ps0, inv1 = 1.0f / ps1;
    *(unsigned*)&naccb[(size_t)(b*256 + x0    )*512 + h*64 + d0] = pk2(a00*inv0, a01*inv0);
    *(unsigned*)&naccb[(size_t)(b*256 + x0 + 1)*512 + h*64 + d0] = pk2(a10*inv1, a11*inv1);
    if (d0 == 0) { sums_s[0][h] = ps0; sums_s[1][h] = ps1; }
  }
  __syncthreads();

  // t8 = attn_sm + residual -> overwrite sbt8
  #pragma unroll
  for (int r = 0; r < 2; r++) {
    float madd = r ? madd1 : madd0;
    float v[8];
    #pragma unroll
    for (int h = 0; h < 8; h++) {
      float inv = 1.0f / sums_s[r][h];
      float pe = __expf(acc[r][h] + madd);
      v[h] = pe*inv + acc[r][h];
    }
    uint4 o;
    o.x = pk2(v[0], v[1]); o.y = pk2(v[2], v[3]);
    o.z = pk2(v[4], v[5]); o.w = pk2(v[6], v[7]);
    sbt8[(size_t)(b*256 + x0 + r)*256 + y] = o;
  }
}

// ---- k_edge: 4 rows x 32-e half per block, 256 threads, grid 2048. ---------
// edge_out = t8 @ ew + eb ; pooled softmax -> pl. Barrier-free after staging.
__global__ __launch_bounds__(256) void k_edge(
    const uint4* __restrict__ sbt8, const unsigned char* __restrict__ mask,
    const float* __restrict__ ew, const float* __restrict__ eb,
    float* __restrict__ out_edge, float* __restrict__ pl)
{
  __shared__ alignas(16) float ew_s[64][8];
  __shared__ alignas(16) float eb_s[64];
  const int t = threadIdx.x;
  const int b = blockIdx.x >> 7;
  const int q7 = blockIdx.x & 127;
  const int x0 = (q7 >> 1) * 4;
  const int e0 = (q7 & 1) * 32;
  for (int i = t; i < 512; i += 256) ((float*)ew_s)[i] = ew[i];
  if (t < 64) eb_s[t] = eb[t];
  __syncthreads();

  const int xi = t >> 6, lane = t & 63;
  const int y0 = lane * 4;
  const int xg = x0 + xi;

  float tf[4][8];
  #pragma unroll
  for (int j = 0; j < 4; j++) {
    uint4 u = sbt8[(size_t)(b*256 + xg)*256 + y0 + j];
    tf[j][0]=blo(u.x); tf[j][1]=bhi(u.x); tf[j][2]=blo(u.y); tf[j][3]=bhi(u.y);
    tf[j][4]=blo(u.z); tf[j][5]=bhi(u.z); tf[j][6]=blo(u.w); tf[j][7]=bhi(u.w);
  }
  uchar4 mb = *(const uchar4*)&mask[(size_t)b*65536 + (size_t)xg*256 + y0];
  const float md[4] = {mb.x ? -1e30f : 0.f, mb.y ? -1e30f : 0.f,
                       mb.z ? -1e30f : 0.f, mb.w ? -1e30f : 0.f};

  for (int ee = 0; ee < 32; ee++) {
    int e = e0 + ee;
    const float4* ewq = (const float4*)ew_s[e];
    float4 w0 = ewq[0], w1 = ewq[1];
    float wh[8] = {w0.x,w0.y,w0.z,w0.w,w1.x,w1.y,w1.z,w1.w};
    float ebv = eb_s[e];
    float eo[4];
    #pragma unroll
    for (int j = 0; j < 4; j++) {
      float s = ebv;
      #pragma unroll
      for (int h = 0; h < 8; h++) s += tf[j][h]*wh[h];
      eo[j] = s;
    }
    float e0v = __expf(eo[0]+md[0]), e1v = __expf(eo[1]+md[1]);
    float e2v = __expf(eo[2]+md[2]), e3v = __expf(eo[3]+md[3]);
    float se  = (e0v + e1v) + (e2v + e3v);
    float swe = (e0v*eo[0] + e1v*eo[1]) + (e2v*eo[2] + e3v*eo[3]);
    se  = wave_sum64(se);
    swe = wave_sum64(swe);
    if (lane == 0) pl[(size_t)(b*256 + xg)*64 + e] = swe / se;
    f4_ ov = {eo[0], eo[1], eo[2], eo[3]};
    __builtin_nontemporal_store(ov,
      (f4_*)&out_edge[((size_t)(b*64 + e)*256 + xg)*256 + y0]);
  }
}

// ---- k_fc: naccb[m][c] += fcb[c] + pl[m] . fcw[c]  (in place, bf16) --------
__global__ __launch_bounds__(256) void k_fc(
    unsigned short* __restrict__ naccb, const float* __restrict__ pl,
    const float* __restrict__ fcw, const float* __restrict__ fcb)
{
  __shared__ alignas(16) float pl_s[2][64];
  const int t = threadIdx.x;
  const int m0 = blockIdx.x * 2;
  if (t < 128) pl_s[t >> 6][t & 63] = pl[(size_t)(m0 + (t >> 6))*64 + (t & 63)];
  __syncthreads();
  const int mi = t >> 7;
  const int c4 = (t & 127) * 4;
  const size_t m = m0 + mi;
  uint2 u = *(const uint2*)&naccb[m*512 + c4];
  float a[4] = {blo(u.x), bhi(u.x), blo(u.y), bhi(u.y)};
  #pragma unroll
  for (int j = 0; j < 4; j++) a[j] += fcb[c4 + j];
  const float4* fw4 = (const float4*)fcw;
  #pragma unroll 4
  for (int e4 = 0; e4 < 16; e4++) {
    float4 p4 = *(const float4*)&pl_s[mi][e4*4];
    #pragma unroll
    for (int j = 0; j < 4; j++) {
      float4 f = fw4[(size_t)(c4 + j)*16 + e4];
      a[j] += p4.x*f.x + p4.y*f.y + p4.z*f.z + p4.w*f.w;
    }
  }
  *(uint2*)&naccb[m*512 + c4] = make_uint2(pk2(a[0], a[1]), pk2(a[2], a[3]));
}

// ---------------- Output projection GEMM + bias (bf16 in) -------------------
__global__ __launch_bounds__(256) void proj_gemm(
    const unsigned short* __restrict__ Xb, const float* __restrict__ W,
    const float* __restrict__ bias, float* __restrict__ out)
{
  __shared__ alignas(16) float A_s[16][136];
  __shared__ alignas(16) float W_s[16][72];
  const int t  = threadIdx.x;
  const int m0 = blockIdx.x * 128;
  const int o0 = blockIdx.y * 64;
  const int tm = (t & 15) * 8;
  const int to = (t >> 4) * 4;
  float acc[8][4];
  #pragma unroll
  for (int i = 0; i < 8; i++)
    #pragma unroll
    for (int j = 0; j < 4; j++) acc[i][j] = 0.f;

  const uint4* X4 = (const uint4*)Xb;
  const float4* W4 = (const float4*)W;
  for (int c0 = 0; c0 < 512; c0 += 16) {
    {
      int row = t >> 1, half = t & 1;
      uint4 a = X4[(size_t)(m0 + row) * 64 + (c0 >> 3) + half];
      int cb = half*8;
      A_s[cb+0][row] = blo(a.x); A_s[cb+1][row] = bhi(a.x);
      A_s[cb+2][row] = blo(a.y); A_s[cb+3][row] = bhi(a.y);
      A_s[cb+4][row] = blo(a.z); A_s[cb+5][row] = bhi(a.z);
      A_s[cb+6][row] = blo(a.w); A_s[cb+7][row] = bhi(a.w);
    }
    {
      int row = t >> 2, quad = t & 3;
      float4 w = W4[(size_t)(o0 + row) * 128 + (c0 >> 2) + quad];
      W_s[quad*4+0][row] = w.x; W_s[quad*4+1][row] = w.y;
      W_s[quad*4+2][row] = w.z; W_s[quad*4+3][row] = w.w;
    }
    __syncthreads();
    #pragma unroll
    for (int kk = 0; kk < 16; kk++) {
      float4 a0 = *(const float4*)&A_s[kk][tm];
      float4 a1 = *(const float4*)&A_s[kk][tm + 4];
      float4 w0 = *(const float4*)&W_s[kk][to];
      float am[8] = {a0.x,a0.y,a0.z,a0.w,a1.x,a1.y,a1.z,a1.w};
      float wn[4] = {w0.x,w0.y,w0.z,w0.w};
      #pragma unroll
      for (int i = 0; i < 8; i++)
        #pragma unroll
        for (int j = 0; j < 4; j++) acc[i][j] += am[i] * wn[j];
    }
    __syncthreads();
  }
  float4 bb = *(const float4*)&bias[o0 + to];
  #pragma unroll
  for (int i = 0; i < 8; i++) {
    int m = m0 + tm + i;
    float4 r = make_float4(acc[i][0]+bb.x, acc[i][1]+bb.y, acc[i][2]+bb.z, acc[i][3]+bb.w);
    *(float4*)&out[(size_t)m*512 + o0 + to] = r;
  }
}

extern "C" void kernel_launch(void* const* d_in, const int* in_sizes, int n_in,
                              void* d_out, int out_size, void* d_ws, size_t ws_size,
                              hipStream_t stream)
{
  (void)in_sizes; (void)n_in; (void)out_size; (void)ws_size;
  const float* node   = (const float*)d_in[0];
  const float* edge   = (const float*)d_in[1];
  const unsigned char* mask = (const unsigned char*)d_in[2];
  const float* qkv_w  = (const float*)d_in[3];
  const float* proj_w = (const float*)d_in[4];
  const float* proj_b = (const float*)d_in[5];
  const float* rw     = (const float*)d_in[6];
  const float* rb     = (const float*)d_in[7];
  const float* ew     = (const float*)d_in[8];
  const float* eb     = (const float*)d_in[9];
  const float* fcw    = (const float*)d_in[10];
  const float* fcb    = (const float*)d_in[11];

  float* out_node = (float*)d_out;
  float* out_edge = out_node + (size_t)16*256*512;

  char* ws = (char*)d_ws;  // ws_size ~1 GB (measured round 8); we use ~34 MB
  unsigned short* qb    = (unsigned short*)(ws);                        // 4 MB
  uint2*          ktq   = (uint2*)         (ws + (size_t)4*1024*1024);  // 4 MB
  uint2*          vq    = (uint2*)         (ws + (size_t)8*1024*1024);  // 4 MB
  uint4*          sbt8  = (uint4*)         (ws + (size_t)12*1024*1024); // 16.8 MB
  unsigned short* naccb = (unsigned short*)(ws + (size_t)12*1024*1024 + 16777216); // 4 MB
  float*          pl    = (float*)         (ws + (size_t)12*1024*1024 + 16777216 + 4194304); // 1 MB

  qkv_gemm <<<dim3(32, 24, 1), 256, 0, stream>>>(node, qkv_w, qb, ktq, vq);
  k_bias   <<<1024, 256, 0, stream>>>(edge, rw, rb, sbt8);
  k_attn   <<<2048, 256, 0, stream>>>(qb, ktq, vq, sbt8, mask, naccb);
  k_edge   <<<2048, 256, 0, stream>>>(sbt8, mask, ew, eb, out_edge, pl);
  k_fc     <<<2048, 256, 0, stream>>>(naccb, pl, fcw, fcb);
  proj_gemm<<<dim3(32, 8, 1), 256, 0, stream>>>(naccb, proj_w, proj_b, out_node);
}

// Round 10
// 327.516 us; speedup vs baseline: 1.4477x; 1.3753x over previous
//
#include <hip/hip_runtime.h>
#include <hip/hip_bf16.h>
#include <cstdint>
#include <cstddef>

#define SCALE_ 0.125f
// B=16 N=256 C=512 H=8 HD=64 E=64

typedef float f4_ __attribute__((ext_vector_type(4)));

__device__ __forceinline__ unsigned pk2(float a, float b) {
  union { __hip_bfloat16 h[2]; unsigned u; } x;
  x.h[0] = __float2bfloat16(a);
  x.h[1] = __float2bfloat16(b);
  return x.u;
}
__device__ __forceinline__ unsigned short bf16b(float a) {
  union { __hip_bfloat16 h; unsigned short s; } x;
  x.h = __float2bfloat16(a);
  return x.s;
}
__device__ __forceinline__ float blo(unsigned u) { return __uint_as_float(u << 16); }
__device__ __forceinline__ float bhi(unsigned u) { return __uint_as_float(u & 0xffff0000u); }

template<int CTRL, int RM>
__device__ __forceinline__ float dppadd(float v) {
  int x = __builtin_amdgcn_update_dpp(0, __float_as_int(v), CTRL, RM, 0xf, true);
  return v + __int_as_float(x);
}
__device__ __forceinline__ float wave_sum64(float v) {
  v = dppadd<0x111, 0xf>(v);   // row_shr:1
  v = dppadd<0x112, 0xf>(v);   // row_shr:2
  v = dppadd<0x114, 0xf>(v);   // row_shr:4
  v = dppadd<0x118, 0xf>(v);   // row_shr:8
  v = dppadd<0x142, 0xa>(v);   // row_bcast:15 -> rows 1,3
  v = dppadd<0x143, 0xc>(v);   // row_bcast:31 -> rows 2,3
  return __int_as_float(__builtin_amdgcn_readlane(__float_as_int(v), 63));
}

// ---------------- Kernel 1: QKV projection GEMM (f32 in, bf16 out) ----------
__global__ __launch_bounds__(256) void qkv_gemm(
    const float* __restrict__ X, const float* __restrict__ W,
    unsigned short* __restrict__ qb, uint2* __restrict__ ktq, uint2* __restrict__ vq)
{
  __shared__ alignas(16) float A_s[16][136];
  __shared__ alignas(16) float W_s[16][72];
  const int t  = threadIdx.x;
  const int m0 = blockIdx.x * 128;
  const int o0 = blockIdx.y * 64;
  const int tm = (t & 15) * 8;
  const int to = (t >> 4) * 4;
  float acc[8][4];
  #pragma unroll
  for (int i = 0; i < 8; i++)
    #pragma unroll
    for (int j = 0; j < 4; j++) acc[i][j] = 0.f;

  const float4* X4 = (const float4*)X;
  const float4* W4 = (const float4*)W;
  for (int c0 = 0; c0 < 512; c0 += 16) {
    #pragma unroll
    for (int i = 0; i < 2; i++) {
      int id = t + 256 * i;
      int row = id >> 2, quad = id & 3;
      float4 a = X4[(size_t)(m0 + row) * 128 + (c0 >> 2) + quad];
      A_s[quad*4+0][row] = a.x; A_s[quad*4+1][row] = a.y;
      A_s[quad*4+2][row] = a.z; A_s[quad*4+3][row] = a.w;
    }
    {
      int row = t >> 2, quad = t & 3;
      float4 w = W4[(size_t)(o0 + row) * 128 + (c0 >> 2) + quad];
      W_s[quad*4+0][row] = w.x; W_s[quad*4+1][row] = w.y;
      W_s[quad*4+2][row] = w.z; W_s[quad*4+3][row] = w.w;
    }
    __syncthreads();
    #pragma unroll
    for (int kk = 0; kk < 16; kk++) {
      float4 a0 = *(const float4*)&A_s[kk][tm];
      float4 a1 = *(const float4*)&A_s[kk][tm + 4];
      float4 w0 = *(const float4*)&W_s[kk][to];
      float am[8] = {a0.x,a0.y,a0.z,a0.w,a1.x,a1.y,a1.z,a1.w};
      float wn[4] = {w0.x,w0.y,w0.z,w0.w};
      #pragma unroll
      for (int i = 0; i < 8; i++)
        #pragma unroll
        for (int j = 0; j < 4; j++) acc[i][j] += am[i] * wn[j];
    }
    __syncthreads();
  }
  const int three = o0 >> 9;
  const int h = (o0 >> 6) & 7;
  if (three == 0) {
    #pragma unroll
    for (int i = 0; i < 8; i++) {
      int m = m0 + tm + i;
      int b = m >> 8, n = m & 255;
      unsigned u0 = pk2(acc[i][0], acc[i][1]);
      unsigned u1 = pk2(acc[i][2], acc[i][3]);
      *(uint2*)&qb[((size_t)(b*8 + h)*256 + n)*64 + to] = make_uint2(u0, u1);
    }
  } else if (three == 1) {
    #pragma unroll
    for (int i = 0; i < 8; i++) {
      int m = m0 + tm + i;
      int b = m >> 8, n = m & 255;
      ktq[(size_t)(b*8 + h)*4096 + (size_t)(to >> 2)*256 + n] =
        make_uint2(pk2(acc[i][0], acc[i][1]), pk2(acc[i][2], acc[i][3]));
    }
  } else {
    int m = m0 + tm;
    int b = m >> 8, n0 = m & 255;
    #pragma unroll
    for (int ii = 0; ii < 2; ii++) {
      #pragma unroll
      for (int j = 0; j < 4; j++) {
        vq[(size_t)(b*8 + h)*4096 + (size_t)((n0 >> 2) + ii)*64 + to + j] =
          make_uint2(pk2(acc[4*ii+0][j], acc[4*ii+1][j]),
                     pk2(acc[4*ii+2][j], acc[4*ii+3][j]));
      }
    }
  }
}

// -------- Kernel 2: fused attn + edge pipeline (2 rows/block, 256t) ---------
// LDS ~30 KB -> 5 blocks/CU. q and p staged as f32 (broadcast reads, no
// per-use unpack); coalesced PV; NT edge streams; DPP pooling.
__global__ __launch_bounds__(256) void fused_attn(
    const unsigned short* __restrict__ qb, const uint2* __restrict__ ktq,
    const uint2* __restrict__ vq,
    const float* __restrict__ edge, const unsigned char* __restrict__ mask,
    const float* __restrict__ rw, const float* __restrict__ rb,
    const float* __restrict__ ew, const float* __restrict__ eb,
    const float* __restrict__ fcw, const float* __restrict__ fcb,
    float* __restrict__ out_edge, unsigned short* __restrict__ tmpb)
{
  __shared__ alignas(16) float q_s[2][8][64];     // 4 KB f32 q
  __shared__ alignas(16) float p_f[2][8][264];    // 16.9 KB: p (f32), later t8
  __shared__ alignas(16) float nacc_s[2][512];    // 4 KB PV result
  __shared__ alignas(16) float rw_s[64][8];       // 2 KB
  __shared__ alignas(16) float ew_s[64][8];       // 2 KB
  __shared__ alignas(16) float eb_s[64];
  __shared__ alignas(16) float pl2[2][64];
  __shared__ alignas(16) float sums_s[2][8];

  const int t = threadIdx.x;
  const int lane = t & 63;
  const int wv = t >> 6;
  const int b = blockIdx.x >> 7;
  const int x0 = (blockIdx.x & 127) * 2;
  const int y = t;

  // ---- phase 1: stage q (f32), weights
  {
    int r = t >> 7, h = (t >> 4) & 7, d0 = (t & 15) * 4;
    uint2 u = *(const uint2*)&qb[((size_t)(b*8 + h)*256 + x0 + r)*64 + d0];
    q_s[r][h][d0+0] = blo(u.x); q_s[r][h][d0+1] = bhi(u.x);
    q_s[r][h][d0+2] = blo(u.y); q_s[r][h][d0+3] = bhi(u.y);
  }
  for (int i = t; i < 512; i += 256) { rw_s[i >> 3][i & 7] = rw[(i & 7)*64 + (i >> 3)]; }
  for (int i = t; i < 512; i += 256) ((float*)ew_s)[i] = ew[i];
  if (t < 64) eb_s[t] = eb[t];
  const float madd0 = mask[(size_t)b*65536 + (size_t)x0*256 + y]       ? -1e30f : 0.f;
  const float madd1 = mask[(size_t)b*65536 + (size_t)x0*256 + 256 + y] ? -1e30f : 0.f;
  __syncthreads();

  // ---- phase 2a: edge bias (268 MB NT read stream, coalesced over y)
  float acc[2][8];
  #pragma unroll
  for (int h = 0; h < 8; h++) { float rv = rb[h]; acc[0][h] = rv; acc[1][h] = rv; }
  {
    const float* ep = edge + (size_t)b*(64*65536) + (size_t)x0*256 + y;
    #pragma unroll 8
    for (int e = 0; e < 64; e++) {
      float v0 = __builtin_nontemporal_load(ep + (size_t)e*65536);
      float v1 = __builtin_nontemporal_load(ep + (size_t)e*65536 + 256);
      const float4* rwq = (const float4*)rw_s[e];
      float4 w0 = rwq[0], w1 = rwq[1];
      float wh[8] = {w0.x,w0.y,w0.z,w0.w,w1.x,w1.y,w1.z,w1.w};
      #pragma unroll
      for (int h = 0; h < 8; h++) {
        acc[0][h] += v0 * wh[h];
        acc[1][h] += v1 * wh[h];
      }
    }
  }

  // ---- phase 2b: QK^T (k uint2 coalesced; q broadcast from LDS f32)
  #pragma unroll 2
  for (int h = 0; h < 8; h++) {
    const uint2* kq = ktq + (size_t)(b*8 + h)*4096 + y;
    float qk0 = 0.f, qk1 = 0.f;
    #pragma unroll
    for (int d8 = 0; d8 < 8; d8++) {
      uint2 k0 = kq[(size_t)(2*d8)*256];
      uint2 k1 = kq[(size_t)(2*d8+1)*256];
      float kv[8] = {blo(k0.x),bhi(k0.x),blo(k0.y),bhi(k0.y),
                     blo(k1.x),bhi(k1.x),blo(k1.y),bhi(k1.y)};
      float4 qa0 = *(const float4*)&q_s[0][h][d8*8];
      float4 qa1 = *(const float4*)&q_s[0][h][d8*8 + 4];
      float4 qb0 = *(const float4*)&q_s[1][h][d8*8];
      float4 qb1 = *(const float4*)&q_s[1][h][d8*8 + 4];
      qk0 += qa0.x*kv[0] + qa0.y*kv[1] + qa0.z*kv[2] + qa0.w*kv[3]
           + qa1.x*kv[4] + qa1.y*kv[5] + qa1.z*kv[6] + qa1.w*kv[7];
      qk1 += qb0.x*kv[0] + qb0.y*kv[1] + qb0.z*kv[2] + qb0.w*kv[3]
           + qb1.x*kv[4] + qb1.y*kv[5] + qb1.z*kv[6] + qb1.w*kv[7];
    }
    acc[0][h] += SCALE_ * qk0;
    acc[1][h] += SCALE_ * qk1;
  }

  // ---- phase 3: p = exp(s + mask) -> LDS f32 (keep p in regs too)
  float p[2][8];
  #pragma unroll
  for (int h = 0; h < 8; h++) {
    p[0][h] = __expf(acc[0][h] + madd0);
    p[1][h] = __expf(acc[1][h] + madd1);
    p_f[0][h][y] = p[0][h];
    p_f[1][h][y] = p[1][h];
  }
  __syncthreads();

  // ---- phase 4: PV. thread -> (h = t>>5, d-pair d0 = (t&31)*2)
  {
    const int h = t >> 5;
    const int i2 = t & 31;
    const int d0 = i2 * 2;
    const uint4* vp4 = (const uint4*)(vq + (size_t)(b*8 + h)*4096);
    float a00 = 0.f, a01 = 0.f, a10 = 0.f, a11 = 0.f;
    float ps0 = 0.f, ps1 = 0.f;
    #pragma unroll 4
    for (int y4 = 0; y4 < 64; y4++) {
      float4 pr0 = *(const float4*)&p_f[0][h][y4*4];
      float4 pr1 = *(const float4*)&p_f[1][h][y4*4];
      uint4 u = vp4[(size_t)y4*32 + i2];
      float va0 = blo(u.x), va1 = bhi(u.x), va2 = blo(u.y), va3 = bhi(u.y);
      float vb0 = blo(u.z), vb1 = bhi(u.z), vb2 = blo(u.w), vb3 = bhi(u.w);
      ps0 += (pr0.x + pr0.y) + (pr0.z + pr0.w);
      ps1 += (pr1.x + pr1.y) + (pr1.z + pr1.w);
      a00 += pr0.x*va0 + pr0.y*va1 + pr0.z*va2 + pr0.w*va3;
      a01 += pr0.x*vb0 + pr0.y*vb1 + pr0.z*vb2 + pr0.w*vb3;
      a10 += pr1.x*va0 + pr1.y*va1 + pr1.z*va2 + pr1.w*va3;
      a11 += pr1.x*vb0 + pr1.y*vb1 + pr1.z*vb2 + pr1.w*vb3;
    }
    float inv0 = 1.0f / ps0, inv1 = 1.0f / ps1;
    *(float2*)&nacc_s[0][h*64 + d0] = make_float2(a00*inv0, a01*inv0);
    *(float2*)&nacc_s[1][h*64 + d0] = make_float2(a10*inv1, a11*inv1);
    if (i2 == 0) { sums_s[0][h] = ps0; sums_s[1][h] = ps1; }
  }
  __syncthreads();

  // ---- phase 4.5: overwrite p_f with t8 = attn_sm + residual (f32)
  #pragma unroll
  for (int h = 0; h < 8; h++) {
    p_f[0][h][y] = p[0][h] * (1.0f / sums_s[0][h]) + acc[0][h];
    p_f[1][h][y] = p[1][h] * (1.0f / sums_s[1][h]) + acc[1][h];
  }
  __syncthreads();

  // ---- phase 5: expand + NT edge_out write + DPP pooling (wave-local)
  {
    const int r = wv & 1;
    const int epar = wv >> 1;
    const int y0 = lane * 4;
    const int xg = x0 + r;
    float4 tf[8];
    #pragma unroll
    for (int h = 0; h < 8; h++) tf[h] = *(const float4*)&p_f[r][h][y0];
    uchar4 mb = *(const uchar4*)&mask[(size_t)b*65536 + (size_t)xg*256 + y0];
    const float md0 = mb.x ? -1e30f : 0.f;
    const float md1 = mb.y ? -1e30f : 0.f;
    const float md2 = mb.z ? -1e30f : 0.f;
    const float md3 = mb.w ? -1e30f : 0.f;
    const float4* ew4 = (const float4*)ew_s;
    for (int ec = 0; ec < 32; ec++) {
      int e = ec*2 + epar;
      float4 w0 = ew4[e*2], w1 = ew4[e*2+1];
      float wh[8] = {w0.x,w0.y,w0.z,w0.w,w1.x,w1.y,w1.z,w1.w};
      float ebv = eb_s[e];
      float eo0 = ebv, eo1 = ebv, eo2 = ebv, eo3 = ebv;
      #pragma unroll
      for (int h = 0; h < 8; h++) {
        float4 tv = tf[h];
        eo0 += tv.x*wh[h];
        eo1 += tv.y*wh[h];
        eo2 += tv.z*wh[h];
        eo3 += tv.w*wh[h];
      }
      float e0v = __expf(eo0+md0), e1v = __expf(eo1+md1);
      float e2v = __expf(eo2+md2), e3v = __expf(eo3+md3);
      float se  = (e0v + e1v) + (e2v + e3v);
      float swe = (e0v*eo0 + e1v*eo1) + (e2v*eo2 + e3v*eo3);
      se  = wave_sum64(se);
      swe = wave_sum64(swe);
      if (lane == 0) pl2[r][e] = swe / se;
      f4_ ov = {eo0, eo1, eo2, eo3};
      __builtin_nontemporal_store(ov,
        (f4_*)&out_edge[((size_t)(b*64 + e)*256 + xg)*256 + y0]);
    }
  }
  __syncthreads();

  // ---- phase 6: node_tmp = PV + pool @ fc_w^T + fc_b  (bf16 out)
  #pragma unroll
  for (int pass = 0; pass < 2; pass++) {
    int cdx = t + pass*256;
    float bias_c = fcb[cdx];
    float a0 = nacc_s[0][cdx] + bias_c;
    float a1 = nacc_s[1][cdx] + bias_c;
    const float4* fw4 = (const float4*)fcw;
    #pragma unroll 4
    for (int e4 = 0; e4 < 16; e4++) {
      float4 pl0 = *(const float4*)&pl2[0][e4*4];
      float4 pl1 = *(const float4*)&pl2[1][e4*4];
      float4 f = fw4[(size_t)cdx*16 + e4];
      a0 += pl0.x*f.x + pl0.y*f.y + pl0.z*f.z + pl0.w*f.w;
      a1 += pl1.x*f.x + pl1.y*f.y + pl1.z*f.z + pl1.w*f.w;
    }
    tmpb[((size_t)b*256 + x0    )*512 + cdx] = bf16b(a0);
    tmpb[((size_t)b*256 + x0 + 1)*512 + cdx] = bf16b(a1);
  }
}

// ---------------- Kernel 3: output projection GEMM + bias (bf16 in) ---------
__global__ __launch_bounds__(256) void proj_gemm(
    const unsigned short* __restrict__ Xb, const float* __restrict__ W,
    const float* __restrict__ bias, float* __restrict__ out)
{
  __shared__ alignas(16) float A_s[16][136];
  __shared__ alignas(16) float W_s[16][72];
  const int t  = threadIdx.x;
  const int m0 = blockIdx.x * 128;
  const int o0 = blockIdx.y * 64;
  const int tm = (t & 15) * 8;
  const int to = (t >> 4) * 4;
  float acc[8][4];
  #pragma unroll
  for (int i = 0; i < 8; i++)
    #pragma unroll
    for (int j = 0; j < 4; j++) acc[i][j] = 0.f;

  const uint4* X4 = (const uint4*)Xb;
  const float4* W4 = (const float4*)W;
  for (int c0 = 0; c0 < 512; c0 += 16) {
    {
      int row = t >> 1, half = t & 1;
      uint4 a = X4[(size_t)(m0 + row) * 64 + (c0 >> 3) + half];
      int cb = half*8;
      A_s[cb+0][row] = blo(a.x); A_s[cb+1][row] = bhi(a.x);
      A_s[cb+2][row] = blo(a.y); A_s[cb+3][row] = bhi(a.y);
      A_s[cb+4][row] = blo(a.z); A_s[cb+5][row] = bhi(a.z);
      A_s[cb+6][row] = blo(a.w); A_s[cb+7][row] = bhi(a.w);
    }
    {
      int row = t >> 2, quad = t & 3;
      float4 w = W4[(size_t)(o0 + row) * 128 + (c0 >> 2) + quad];
      W_s[quad*4+0][row] = w.x; W_s[quad*4+1][row] = w.y;
      W_s[quad*4+2][row] = w.z; W_s[quad*4+3][row] = w.w;
    }
    __syncthreads();
    #pragma unroll
    for (int kk = 0; kk < 16; kk++) {
      float4 a0 = *(const float4*)&A_s[kk][tm];
      float4 a1 = *(const float4*)&A_s[kk][tm + 4];
      float4 w0 = *(const float4*)&W_s[kk][to];
      float am[8] = {a0.x,a0.y,a0.z,a0.w,a1.x,a1.y,a1.z,a1.w};
      float wn[4] = {w0.x,w0.y,w0.z,w0.w};
      #pragma unroll
      for (int i = 0; i < 8; i++)
        #pragma unroll
        for (int j = 0; j < 4; j++) acc[i][j] += am[i] * wn[j];
    }
    __syncthreads();
  }
  float4 bb = *(const float4*)&bias[o0 + to];
  #pragma unroll
  for (int i = 0; i < 8; i++) {
    int m = m0 + tm + i;
    float4 r = make_float4(acc[i][0]+bb.x, acc[i][1]+bb.y, acc[i][2]+bb.z, acc[i][3]+bb.w);
    *(float4*)&out[(size_t)m*512 + o0 + to] = r;
  }
}

extern "C" void kernel_launch(void* const* d_in, const int* in_sizes, int n_in,
                              void* d_out, int out_size, void* d_ws, size_t ws_size,
                              hipStream_t stream)
{
  (void)in_sizes; (void)n_in; (void)out_size; (void)ws_size;
  const float* node   = (const float*)d_in[0];
  const float* edge   = (const float*)d_in[1];
  const unsigned char* mask = (const unsigned char*)d_in[2];
  const float* qkv_w  = (const float*)d_in[3];
  const float* proj_w = (const float*)d_in[4];
  const float* proj_b = (const float*)d_in[5];
  const float* rw     = (const float*)d_in[6];
  const float* rb     = (const float*)d_in[7];
  const float* ew     = (const float*)d_in[8];
  const float* eb     = (const float*)d_in[9];
  const float* fcw    = (const float*)d_in[10];
  const float* fcb    = (const float*)d_in[11];

  float* out_node = (float*)d_out;
  float* out_edge = out_node + (size_t)16*256*512;

  char* ws = (char*)d_ws;
  unsigned short* qb  = (unsigned short*)(ws);                    // 4 MB
  uint2*          ktq = (uint2*)         (ws + (size_t)4*1024*1024);
  uint2*          vq  = (uint2*)         (ws + (size_t)8*1024*1024);
  unsigned short* tmpb= (unsigned short*)(ws + (size_t)12*1024*1024);

  qkv_gemm <<<dim3(32, 24, 1), 256, 0, stream>>>(node, qkv_w, qb, ktq, vq);
  fused_attn<<<dim3(2048, 1, 1), 256, 0, stream>>>(qb, ktq, vq, edge, mask,
                                                   rw, rb, ew, eb, fcw, fcb,
                                                   out_edge, tmpb);
  proj_gemm<<<dim3(32, 8, 1), 256, 0, stream>>>(tmpb, proj_w, proj_b, out_node);
}

// Round 11
// 289.858 us; speedup vs baseline: 1.6358x; 1.1299x over previous
//
#include <hip/hip_runtime.h>
#include <hip/hip_bf16.h>
#include <cstdint>
#include <cstddef>

#define SCALE_ 0.125f
// B=16 N=256 C=512 H=8 HD=64 E=64

typedef float f4_ __attribute__((ext_vector_type(4)));
typedef __bf16 bf2_ __attribute__((ext_vector_type(2)));

__device__ __forceinline__ unsigned pk2(float a, float b) {
  union { __hip_bfloat16 h[2]; unsigned u; } x;
  x.h[0] = __float2bfloat16(a);
  x.h[1] = __float2bfloat16(b);
  return x.u;
}
__device__ __forceinline__ unsigned short bf16b(float a) {
  union { __hip_bfloat16 h; unsigned short s; } x;
  x.h = __float2bfloat16(a);
  return x.s;
}
__device__ __forceinline__ float blo(unsigned u) { return __uint_as_float(u << 16); }
__device__ __forceinline__ float bhi(unsigned u) { return __uint_as_float(u & 0xffff0000u); }

// packed bf16 pair dot: d = a.lo*b.lo + a.hi*b.hi + c  (one VALU op on gfx950)
__device__ __forceinline__ float dot2b(unsigned a, unsigned b, float c) {
#if __has_builtin(__builtin_amdgcn_fdot2_f32_bf16)
  return __builtin_amdgcn_fdot2_f32_bf16(__builtin_bit_cast(bf2_, a),
                                         __builtin_bit_cast(bf2_, b), c, false);
#else
  return fmaf(blo(a), blo(b), fmaf(bhi(a), bhi(b), c));
#endif
}

template<int CTRL, int RM>
__device__ __forceinline__ float dppadd(float v) {
  int x = __builtin_amdgcn_update_dpp(0, __float_as_int(v), CTRL, RM, 0xf, true);
  return v + __int_as_float(x);
}
__device__ __forceinline__ float wave_sum64(float v) {
  v = dppadd<0x111, 0xf>(v);   // row_shr:1
  v = dppadd<0x112, 0xf>(v);   // row_shr:2
  v = dppadd<0x114, 0xf>(v);   // row_shr:4
  v = dppadd<0x118, 0xf>(v);   // row_shr:8
  v = dppadd<0x142, 0xa>(v);   // row_bcast:15 -> rows 1,3
  v = dppadd<0x143, 0xc>(v);   // row_bcast:31 -> rows 2,3
  return __int_as_float(__builtin_amdgcn_readlane(__float_as_int(v), 63));
}

// ---------------- Kernel 1: QKV projection GEMM (f32 in, bf16 out) ----------
__global__ __launch_bounds__(256) void qkv_gemm(
    const float* __restrict__ X, const float* __restrict__ W,
    unsigned short* __restrict__ qb, uint2* __restrict__ ktq, uint2* __restrict__ vq)
{
  __shared__ alignas(16) float A_s[16][136];
  __shared__ alignas(16) float W_s[16][72];
  const int t  = threadIdx.x;
  const int m0 = blockIdx.x * 128;
  const int o0 = blockIdx.y * 64;
  const int tm = (t & 15) * 8;
  const int to = (t >> 4) * 4;
  float acc[8][4];
  #pragma unroll
  for (int i = 0; i < 8; i++)
    #pragma unroll
    for (int j = 0; j < 4; j++) acc[i][j] = 0.f;

  const float4* X4 = (const float4*)X;
  const float4* W4 = (const float4*)W;
  for (int c0 = 0; c0 < 512; c0 += 16) {
    #pragma unroll
    for (int i = 0; i < 2; i++) {
      int id = t + 256 * i;
      int row = id >> 2, quad = id & 3;
      float4 a = X4[(size_t)(m0 + row) * 128 + (c0 >> 2) + quad];
      A_s[quad*4+0][row] = a.x; A_s[quad*4+1][row] = a.y;
      A_s[quad*4+2][row] = a.z; A_s[quad*4+3][row] = a.w;
    }
    {
      int row = t >> 2, quad = t & 3;
      float4 w = W4[(size_t)(o0 + row) * 128 + (c0 >> 2) + quad];
      W_s[quad*4+0][row] = w.x; W_s[quad*4+1][row] = w.y;
      W_s[quad*4+2][row] = w.z; W_s[quad*4+3][row] = w.w;
    }
    __syncthreads();
    #pragma unroll
    for (int kk = 0; kk < 16; kk++) {
      float4 a0 = *(const float4*)&A_s[kk][tm];
      float4 a1 = *(const float4*)&A_s[kk][tm + 4];
      float4 w0 = *(const float4*)&W_s[kk][to];
      float am[8] = {a0.x,a0.y,a0.z,a0.w,a1.x,a1.y,a1.z,a1.w};
      float wn[4] = {w0.x,w0.y,w0.z,w0.w};
      #pragma unroll
      for (int i = 0; i < 8; i++)
        #pragma unroll
        for (int j = 0; j < 4; j++) acc[i][j] += am[i] * wn[j];
    }
    __syncthreads();
  }
  const int three = o0 >> 9;
  const int h = (o0 >> 6) & 7;
  if (three == 0) {
    #pragma unroll
    for (int i = 0; i < 8; i++) {
      int m = m0 + tm + i;
      int b = m >> 8, n = m & 255;
      unsigned u0 = pk2(acc[i][0], acc[i][1]);
      unsigned u1 = pk2(acc[i][2], acc[i][3]);
      *(uint2*)&qb[((size_t)(b*8 + h)*256 + n)*64 + to] = make_uint2(u0, u1);
    }
  } else if (three == 1) {
    #pragma unroll
    for (int i = 0; i < 8; i++) {
      int m = m0 + tm + i;
      int b = m >> 8, n = m & 255;
      ktq[(size_t)(b*8 + h)*4096 + (size_t)(to >> 2)*256 + n] =
        make_uint2(pk2(acc[i][0], acc[i][1]), pk2(acc[i][2], acc[i][3]));
    }
  } else {
    int m = m0 + tm;
    int b = m >> 8, n0 = m & 255;
    #pragma unroll
    for (int ii = 0; ii < 2; ii++) {
      #pragma unroll
      for (int j = 0; j < 4; j++) {
        vq[(size_t)(b*8 + h)*4096 + (size_t)((n0 >> 2) + ii)*64 + to + j] =
          make_uint2(pk2(acc[4*ii+0][j], acc[4*ii+1][j]),
                     pk2(acc[4*ii+2][j], acc[4*ii+3][j]));
      }
    }
  }
}

// -------- Kernel 2: fused attn + edge pipeline (2 rows/block, 256t) ---------
// Inner loops on v_dot2_f32_bf16 (packed bf16 MACs). LDS ~17.5 KB.
__global__ __launch_bounds__(256) void fused_attn(
    const unsigned short* __restrict__ qb, const uint2* __restrict__ ktq,
    const uint2* __restrict__ vq,
    const float* __restrict__ edge, const unsigned char* __restrict__ mask,
    const float* __restrict__ rw, const float* __restrict__ rb,
    const float* __restrict__ ew, const float* __restrict__ eb,
    const float* __restrict__ fcw, const float* __restrict__ fcb,
    float* __restrict__ out_edge, unsigned short* __restrict__ tmpb)
{
  __shared__ alignas(16) unsigned q_pk[2][8][32];      // 2 KB packed q (d-pairs)
  __shared__ alignas(16) unsigned char pt_raw[8448];   // p (bf16) then t8 (h-pairs)
  __shared__ alignas(16) float nacc_s[2][512];         // 4 KB PV result
  __shared__ alignas(16) unsigned rw_pk[32][8];        // 1 KB rw e-pairs [ep][h]
  __shared__ alignas(16) unsigned ew_pk[64][4];        // 1 KB ew h-pairs [e][hp]
  __shared__ alignas(16) float eb_s[64];
  __shared__ alignas(16) float pl2[2][64];
  __shared__ alignas(16) float inv_s[2][8];            // 1/sum

  unsigned short (*p_sb)[8][264] = (unsigned short (*)[8][264])pt_raw; // [r][h][y]
  unsigned (*t8_pk)[4][264] = (unsigned (*)[4][264])pt_raw;            // [r][hp][y]

  const int t = threadIdx.x;
  const int lane = t & 63;
  const int wv = t >> 6;
  const int b = blockIdx.x >> 7;
  const int x0 = (blockIdx.x & 127) * 2;
  const int y = t;

  // ---- phase 1: stage q packed, rw/ew pairs, eb
  {
    int r = t >> 7, h = (t >> 4) & 7, d0 = (t & 15) * 4;
    uint2 u = *(const uint2*)&qb[((size_t)(b*8 + h)*256 + x0 + r)*64 + d0];
    q_pk[r][h][(d0 >> 1)]     = u.x;
    q_pk[r][h][(d0 >> 1) + 1] = u.y;
  }
  { int epx = t >> 3, h = t & 7;
    rw_pk[epx][h] = pk2(rw[h*64 + 2*epx], rw[h*64 + 2*epx + 1]); }
  { int e = t >> 2, hp = t & 3;
    ew_pk[e][hp] = pk2(ew[(size_t)e*8 + 2*hp], ew[(size_t)e*8 + 2*hp + 1]); }
  if (t < 64) eb_s[t] = eb[t];
  const float madd0 = mask[(size_t)b*65536 + (size_t)x0*256 + y]       ? -1e30f : 0.f;
  const float madd1 = mask[(size_t)b*65536 + (size_t)x0*256 + 256 + y] ? -1e30f : 0.f;
  __syncthreads();

  // ---- phase 2a: edge bias (NT stream, e-pairs -> dot2)
  float acc[2][8];
  #pragma unroll
  for (int h = 0; h < 8; h++) { float rv = rb[h]; acc[0][h] = rv; acc[1][h] = rv; }
  {
    const float* ep = edge + (size_t)b*(64*65536) + (size_t)x0*256 + y;
    #pragma unroll 4
    for (int e2 = 0; e2 < 32; e2++) {
      float a0 = __builtin_nontemporal_load(ep + (size_t)(2*e2)*65536);
      float a1 = __builtin_nontemporal_load(ep + (size_t)(2*e2)*65536 + 256);
      float b0 = __builtin_nontemporal_load(ep + (size_t)(2*e2+1)*65536);
      float b1 = __builtin_nontemporal_load(ep + (size_t)(2*e2+1)*65536 + 256);
      unsigned v0p = pk2(a0, b0);   // row 0: pair (e, e+1)
      unsigned v1p = pk2(a1, b1);   // row 1
      uint4 w0 = *(const uint4*)&rw_pk[e2][0];
      uint4 w1 = *(const uint4*)&rw_pk[e2][4];
      acc[0][0] = dot2b(v0p, w0.x, acc[0][0]);
      acc[0][1] = dot2b(v0p, w0.y, acc[0][1]);
      acc[0][2] = dot2b(v0p, w0.z, acc[0][2]);
      acc[0][3] = dot2b(v0p, w0.w, acc[0][3]);
      acc[0][4] = dot2b(v0p, w1.x, acc[0][4]);
      acc[0][5] = dot2b(v0p, w1.y, acc[0][5]);
      acc[0][6] = dot2b(v0p, w1.z, acc[0][6]);
      acc[0][7] = dot2b(v0p, w1.w, acc[0][7]);
      acc[1][0] = dot2b(v1p, w0.x, acc[1][0]);
      acc[1][1] = dot2b(v1p, w0.y, acc[1][1]);
      acc[1][2] = dot2b(v1p, w0.z, acc[1][2]);
      acc[1][3] = dot2b(v1p, w0.w, acc[1][3]);
      acc[1][4] = dot2b(v1p, w1.x, acc[1][4]);
      acc[1][5] = dot2b(v1p, w1.y, acc[1][5]);
      acc[1][6] = dot2b(v1p, w1.z, acc[1][6]);
      acc[1][7] = dot2b(v1p, w1.w, acc[1][7]);
    }
  }

  // ---- phase 2b: QK^T (packed k x packed q -> dot2)
  #pragma unroll 2
  for (int h = 0; h < 8; h++) {
    const uint2* kq = ktq + (size_t)(b*8 + h)*4096 + y;
    float qk0 = 0.f, qk1 = 0.f;
    #pragma unroll
    for (int d4 = 0; d4 < 16; d4++) {
      uint2 k = kq[(size_t)d4*256];
      uint2 qa = *(const uint2*)&q_pk[0][h][d4*2];
      uint2 qc = *(const uint2*)&q_pk[1][h][d4*2];
      qk0 = dot2b(k.x, qa.x, qk0);
      qk0 = dot2b(k.y, qa.y, qk0);
      qk1 = dot2b(k.x, qc.x, qk1);
      qk1 = dot2b(k.y, qc.y, qk1);
    }
    acc[0][h] += SCALE_ * qk0;
    acc[1][h] += SCALE_ * qk1;
  }

  // ---- phase 3: p = exp(s + mask) -> bf16 LDS (p kept f32 in regs)
  float p[2][8];
  #pragma unroll
  for (int h = 0; h < 8; h++) {
    p[0][h] = __expf(acc[0][h] + madd0);
    p[1][h] = __expf(acc[1][h] + madd1);
    p_sb[0][h][y] = bf16b(p[0][h]);
    p_sb[1][h][y] = bf16b(p[1][h]);
  }
  __syncthreads();

  // ---- phase 4: PV via dot2 (v y-pairs x p y-pairs); psum via dot2 w/ ones
  {
    const int h = t >> 5;
    const int i2 = t & 31;
    const int d0 = i2 * 2;
    const unsigned ONES = 0x3F803F80u;   // bf16 {1.0, 1.0}
    const uint4* vp4 = (const uint4*)(vq + (size_t)(b*8 + h)*4096);
    float a00 = 0.f, a01 = 0.f, a10 = 0.f, a11 = 0.f;
    float ps0 = 0.f, ps1 = 0.f;
    #pragma unroll 4
    for (int y4 = 0; y4 < 64; y4++) {
      uint2 pp0 = *(const uint2*)&p_sb[0][h][y4*4];
      uint2 pp1 = *(const uint2*)&p_sb[1][h][y4*4];
      uint4 u = vp4[(size_t)y4*32 + i2];
      a00 = dot2b(pp0.x, u.x, a00); a00 = dot2b(pp0.y, u.y, a00);
      a01 = dot2b(pp0.x, u.z, a01); a01 = dot2b(pp0.y, u.w, a01);
      a10 = dot2b(pp1.x, u.x, a10); a10 = dot2b(pp1.y, u.y, a10);
      a11 = dot2b(pp1.x, u.z, a11); a11 = dot2b(pp1.y, u.w, a11);
      ps0 = dot2b(pp0.x, ONES, ps0); ps0 = dot2b(pp0.y, ONES, ps0);
      ps1 = dot2b(pp1.x, ONES, ps1); ps1 = dot2b(pp1.y, ONES, ps1);
    }
    float inv0 = 1.0f / ps0, inv1 = 1.0f / ps1;
    *(float2*)&nacc_s[0][h*64 + d0] = make_float2(a00*inv0, a01*inv0);
    *(float2*)&nacc_s[1][h*64 + d0] = make_float2(a10*inv1, a11*inv1);
    if (i2 == 0) { inv_s[0][h] = inv0; inv_s[1][h] = inv1; }
  }
  __syncthreads();   // p_sb fully consumed; nacc + inv ready

  // ---- phase 4.5: t8 = attn_sm + residual -> packed h-pairs (aliases p_sb)
  #pragma unroll
  for (int r = 0; r < 2; r++) {
    float v[8];
    #pragma unroll
    for (int h = 0; h < 8; h++) v[h] = p[r][h]*inv_s[r][h] + acc[r][h];
    t8_pk[r][0][y] = pk2(v[0], v[1]);
    t8_pk[r][1][y] = pk2(v[2], v[3]);
    t8_pk[r][2][y] = pk2(v[4], v[5]);
    t8_pk[r][3][y] = pk2(v[6], v[7]);
  }
  __syncthreads();

  // ---- phase 5: expand via dot2 + NT edge_out write + DPP pooling
  {
    const int r = wv & 1;
    const int epar = wv >> 1;
    const int y0 = lane * 4;
    const int xg = x0 + r;
    uint4 tfq[4];
    #pragma unroll
    for (int hp = 0; hp < 4; hp++) tfq[hp] = *(const uint4*)&t8_pk[r][hp][y0];
    uchar4 mb = *(const uchar4*)&mask[(size_t)b*65536 + (size_t)xg*256 + y0];
    const float md0 = mb.x ? -1e30f : 0.f;
    const float md1 = mb.y ? -1e30f : 0.f;
    const float md2 = mb.z ? -1e30f : 0.f;
    const float md3 = mb.w ? -1e30f : 0.f;
    for (int ec = 0; ec < 32; ec++) {
      int e = ec*2 + epar;
      uint4 w = *(const uint4*)&ew_pk[e][0];
      float ebv = eb_s[e];
      float eo0 = dot2b(tfq[3].x, w.w, dot2b(tfq[2].x, w.z,
                  dot2b(tfq[1].x, w.y, dot2b(tfq[0].x, w.x, ebv))));
      float eo1 = dot2b(tfq[3].y, w.w, dot2b(tfq[2].y, w.z,
                  dot2b(tfq[1].y, w.y, dot2b(tfq[0].y, w.x, ebv))));
      float eo2 = dot2b(tfq[3].z, w.w, dot2b(tfq[2].z, w.z,
                  dot2b(tfq[1].z, w.y, dot2b(tfq[0].z, w.x, ebv))));
      float eo3 = dot2b(tfq[3].w, w.w, dot2b(tfq[2].w, w.z,
                  dot2b(tfq[1].w, w.y, dot2b(tfq[0].w, w.x, ebv))));
      float e0v = __expf(eo0+md0), e1v = __expf(eo1+md1);
      float e2v = __expf(eo2+md2), e3v = __expf(eo3+md3);
      float se  = (e0v + e1v) + (e2v + e3v);
      float swe = (e0v*eo0 + e1v*eo1) + (e2v*eo2 + e3v*eo3);
      se  = wave_sum64(se);
      swe = wave_sum64(swe);
      if (lane == 0) pl2[r][e] = swe / se;
      f4_ ov = {eo0, eo1, eo2, eo3};
      __builtin_nontemporal_store(ov,
        (f4_*)&out_edge[((size_t)(b*64 + e)*256 + xg)*256 + y0]);
    }
  }
  __syncthreads();

  // ---- phase 6: node_tmp = PV + pool @ fc_w^T + fc_b  (bf16 out)
  #pragma unroll
  for (int pass = 0; pass < 2; pass++) {
    int cdx = t + pass*256;
    float bias_c = fcb[cdx];
    float a0 = nacc_s[0][cdx] + bias_c;
    float a1 = nacc_s[1][cdx] + bias_c;
    const float4* fw4 = (const float4*)fcw;
    #pragma unroll 4
    for (int e4 = 0; e4 < 16; e4++) {
      float4 pl0 = *(const float4*)&pl2[0][e4*4];
      float4 pl1 = *(const float4*)&pl2[1][e4*4];
      float4 f = fw4[(size_t)cdx*16 + e4];
      a0 += pl0.x*f.x + pl0.y*f.y + pl0.z*f.z + pl0.w*f.w;
      a1 += pl1.x*f.x + pl1.y*f.y + pl1.z*f.z + pl1.w*f.w;
    }
    tmpb[((size_t)b*256 + x0    )*512 + cdx] = bf16b(a0);
    tmpb[((size_t)b*256 + x0 + 1)*512 + cdx] = bf16b(a1);
  }
}

// ---------------- Kernel 3: output projection GEMM + bias (bf16 in) ---------
__global__ __launch_bounds__(256) void proj_gemm(
    const unsigned short* __restrict__ Xb, const float* __restrict__ W,
    const float* __restrict__ bias, float* __restrict__ out)
{
  __shared__ alignas(16) float A_s[16][136];
  __shared__ alignas(16) float W_s[16][72];
  const int t  = threadIdx.x;
  const int m0 = blockIdx.x * 128;
  const int o0 = blockIdx.y * 64;
  const int tm = (t & 15) * 8;
  const int to = (t >> 4) * 4;
  float acc[8][4];
  #pragma unroll
  for (int i = 0; i < 8; i++)
    #pragma unroll
    for (int j = 0; j < 4; j++) acc[i][j] = 0.f;

  const uint4* X4 = (const uint4*)Xb;
  const float4* W4 = (const float4*)W;
  for (int c0 = 0; c0 < 512; c0 += 16) {
    {
      int row = t >> 1, half = t & 1;
      uint4 a = X4[(size_t)(m0 + row) * 64 + (c0 >> 3) + half];
      int cb = half*8;
      A_s[cb+0][row] = blo(a.x); A_s[cb+1][row] = bhi(a.x);
      A_s[cb+2][row] = blo(a.y); A_s[cb+3][row] = bhi(a.y);
      A_s[cb+4][row] = blo(a.z); A_s[cb+5][row] = bhi(a.z);
      A_s[cb+6][row] = blo(a.w); A_s[cb+7][row] = bhi(a.w);
    }
    {
      int row = t >> 2, quad = t & 3;
      float4 w = W4[(size_t)(o0 + row) * 128 + (c0 >> 2) + quad];
      W_s[quad*4+0][row] = w.x; W_s[quad*4+1][row] = w.y;
      W_s[quad*4+2][row] = w.z; W_s[quad*4+3][row] = w.w;
    }
    __syncthreads();
    #pragma unroll
    for (int kk = 0; kk < 16; kk++) {
      float4 a0 = *(const float4*)&A_s[kk][tm];
      float4 a1 = *(const float4*)&A_s[kk][tm + 4];
      float4 w0 = *(const float4*)&W_s[kk][to];
      float am[8] = {a0.x,a0.y,a0.z,a0.w,a1.x,a1.y,a1.z,a1.w};
      float wn[4] = {w0.x,w0.y,w0.z,w0.w};
      #pragma unroll
      for (int i = 0; i < 8; i++)
        #pragma unroll
        for (int j = 0; j < 4; j++) acc[i][j] += am[i] * wn[j];
    }
    __syncthreads();
  }
  float4 bb = *(const float4*)&bias[o0 + to];
  #pragma unroll
  for (int i = 0; i < 8; i++) {
    int m = m0 + tm + i;
    float4 r = make_float4(acc[i][0]+bb.x, acc[i][1]+bb.y, acc[i][2]+bb.z, acc[i][3]+bb.w);
    *(float4*)&out[(size_t)m*512 + o0 + to] = r;
  }
}

extern "C" void kernel_launch(void* const* d_in, const int* in_sizes, int n_in,
                              void* d_out, int out_size, void* d_ws, size_t ws_size,
                              hipStream_t stream)
{
  (void)in_sizes; (void)n_in; (void)out_size; (void)ws_size;
  const float* node   = (const float*)d_in[0];
  const float* edge   = (const float*)d_in[1];
  const unsigned char* mask = (const unsigned char*)d_in[2];
  const float* qkv_w  = (const float*)d_in[3];
  const float* proj_w = (const float*)d_in[4];
  const float* proj_b = (const float*)d_in[5];
  const float* rw     = (const float*)d_in[6];
  const float* rb     = (const float*)d_in[7];
  const float* ew     = (const float*)d_in[8];
  const float* eb     = (const float*)d_in[9];
  const float* fcw    = (const float*)d_in[10];
  const float* fcb    = (const float*)d_in[11];

  float* out_node = (float*)d_out;
  float* out_edge = out_node + (size_t)16*256*512;

  char* ws = (char*)d_ws;
  unsigned short* qb  = (unsigned short*)(ws);                    // 4 MB
  uint2*          ktq = (uint2*)         (ws + (size_t)4*1024*1024);
  uint2*          vq  = (uint2*)         (ws + (size_t)8*1024*1024);
  unsigned short* tmpb= (unsigned short*)(ws + (size_t)12*1024*1024);

  qkv_gemm <<<dim3(32, 24, 1), 256, 0, stream>>>(node, qkv_w, qb, ktq, vq);
  fused_attn<<<dim3(2048, 1, 1), 256, 0, stream>>>(qb, ktq, vq, edge, mask,
                                                   rw, rb, ew, eb, fcw, fcb,
                                                   out_edge, tmpb);
  proj_gemm<<<dim3(32, 8, 1), 256, 0, stream>>>(tmpb, proj_w, proj_b, out_node);
}

// Round 12
// 255.208 us; speedup vs baseline: 1.8579x; 1.1358x over previous
//
#include <hip/hip_runtime.h>
#include <hip/hip_bf16.h>
#include <cstdint>
#include <cstddef>

#define SCALE_ 0.125f
// B=16 N=256 C=512 H=8 HD=64 E=64

typedef float f4_ __attribute__((ext_vector_type(4)));
typedef __bf16 bf2_ __attribute__((ext_vector_type(2)));

__device__ __forceinline__ unsigned pk2(float a, float b) {
  union { __hip_bfloat16 h[2]; unsigned u; } x;
  x.h[0] = __float2bfloat16(a);
  x.h[1] = __float2bfloat16(b);
  return x.u;
}
__device__ __forceinline__ unsigned short bf16b(float a) {
  union { __hip_bfloat16 h; unsigned short s; } x;
  x.h = __float2bfloat16(a);
  return x.s;
}
__device__ __forceinline__ float blo(unsigned u) { return __uint_as_float(u << 16); }
__device__ __forceinline__ float bhi(unsigned u) { return __uint_as_float(u & 0xffff0000u); }

// packed bf16 pair dot: d = a.lo*b.lo + a.hi*b.hi + c  (one VALU op on gfx950)
__device__ __forceinline__ float dot2b(unsigned a, unsigned b, float c) {
#if __has_builtin(__builtin_amdgcn_fdot2_f32_bf16)
  return __builtin_amdgcn_fdot2_f32_bf16(__builtin_bit_cast(bf2_, a),
                                         __builtin_bit_cast(bf2_, b), c, false);
#else
  return fmaf(blo(a), blo(b), fmaf(bhi(a), bhi(b), c));
#endif
}

template<int CTRL, int RM>
__device__ __forceinline__ float dppadd(float v) {
  int x = __builtin_amdgcn_update_dpp(0, __float_as_int(v), CTRL, RM, 0xf, true);
  return v + __int_as_float(x);
}
__device__ __forceinline__ float wave_sum64(float v) {
  v = dppadd<0x111, 0xf>(v);   // row_shr:1
  v = dppadd<0x112, 0xf>(v);   // row_shr:2
  v = dppadd<0x114, 0xf>(v);   // row_shr:4
  v = dppadd<0x118, 0xf>(v);   // row_shr:8
  v = dppadd<0x142, 0xa>(v);   // row_bcast:15 -> rows 1,3
  v = dppadd<0x143, 0xc>(v);   // row_bcast:31 -> rows 2,3
  return __int_as_float(__builtin_amdgcn_readlane(__float_as_int(v), 63));
}

// ------- Kernel 1: QKV projection GEMM (bf16 dot2, f32 in, bf16 out) --------
__global__ __launch_bounds__(256) void qkv_gemm(
    const float* __restrict__ X, const float* __restrict__ W,
    unsigned short* __restrict__ qb, uint2* __restrict__ ktq, uint2* __restrict__ vq)
{
  __shared__ alignas(16) unsigned A_pk[8][132];   // [kpair][row] packed bf16
  __shared__ alignas(16) unsigned W_pk[8][68];    // [kpair][col]
  const int t  = threadIdx.x;
  const int m0 = blockIdx.x * 128;
  const int o0 = blockIdx.y * 64;
  const int tm = (t & 15) * 8;
  const int to = (t >> 4) * 4;
  float acc[8][4];
  #pragma unroll
  for (int i = 0; i < 8; i++)
    #pragma unroll
    for (int j = 0; j < 4; j++) acc[i][j] = 0.f;

  const float4* X4 = (const float4*)X;
  const float4* W4 = (const float4*)W;
  for (int c0 = 0; c0 < 512; c0 += 16) {
    #pragma unroll
    for (int i = 0; i < 2; i++) {
      int id = t + 256 * i;
      int row = id >> 2, quad = id & 3;
      float4 a = X4[(size_t)(m0 + row) * 128 + (c0 >> 2) + quad];
      A_pk[quad*2    ][row] = pk2(a.x, a.y);
      A_pk[quad*2 + 1][row] = pk2(a.z, a.w);
    }
    {
      int row = t >> 2, quad = t & 3;
      float4 w = W4[(size_t)(o0 + row) * 128 + (c0 >> 2) + quad];
      W_pk[quad*2    ][row] = pk2(w.x, w.y);
      W_pk[quad*2 + 1][row] = pk2(w.z, w.w);
    }
    __syncthreads();
    #pragma unroll
    for (int kp = 0; kp < 8; kp++) {
      uint4 a0 = *(const uint4*)&A_pk[kp][tm];
      uint4 a1 = *(const uint4*)&A_pk[kp][tm + 4];
      uint4 w0 = *(const uint4*)&W_pk[kp][to];
      unsigned am[8] = {a0.x,a0.y,a0.z,a0.w,a1.x,a1.y,a1.z,a1.w};
      unsigned wn[4] = {w0.x,w0.y,w0.z,w0.w};
      #pragma unroll
      for (int i = 0; i < 8; i++)
        #pragma unroll
        for (int j = 0; j < 4; j++) acc[i][j] = dot2b(am[i], wn[j], acc[i][j]);
    }
    __syncthreads();
  }
  const int three = o0 >> 9;
  const int h = (o0 >> 6) & 7;
  if (three == 0) {
    #pragma unroll
    for (int i = 0; i < 8; i++) {
      int m = m0 + tm + i;
      int b = m >> 8, n = m & 255;
      unsigned u0 = pk2(acc[i][0], acc[i][1]);
      unsigned u1 = pk2(acc[i][2], acc[i][3]);
      *(uint2*)&qb[((size_t)(b*8 + h)*256 + n)*64 + to] = make_uint2(u0, u1);
    }
  } else if (three == 1) {
    #pragma unroll
    for (int i = 0; i < 8; i++) {
      int m = m0 + tm + i;
      int b = m >> 8, n = m & 255;
      ktq[(size_t)(b*8 + h)*4096 + (size_t)(to >> 2)*256 + n] =
        make_uint2(pk2(acc[i][0], acc[i][1]), pk2(acc[i][2], acc[i][3]));
    }
  } else {
    int m = m0 + tm;
    int b = m >> 8, n0 = m & 255;
    #pragma unroll
    for (int ii = 0; ii < 2; ii++) {
      #pragma unroll
      for (int j = 0; j < 4; j++) {
        vq[(size_t)(b*8 + h)*4096 + (size_t)((n0 >> 2) + ii)*64 + to + j] =
          make_uint2(pk2(acc[4*ii+0][j], acc[4*ii+1][j]),
                     pk2(acc[4*ii+2][j], acc[4*ii+3][j]));
      }
    }
  }
}

// -------- Kernel 2: fused attn + edge pipeline (2 rows/block, 256t) ---------
// Inner loops on v_dot2_f32_bf16 (packed bf16 MACs). LDS ~17.5 KB.
__global__ __launch_bounds__(256) void fused_attn(
    const unsigned short* __restrict__ qb, const uint2* __restrict__ ktq,
    const uint2* __restrict__ vq,
    const float* __restrict__ edge, const unsigned char* __restrict__ mask,
    const float* __restrict__ rw, const float* __restrict__ rb,
    const float* __restrict__ ew, const float* __restrict__ eb,
    const float* __restrict__ fcw, const float* __restrict__ fcb,
    float* __restrict__ out_edge, unsigned short* __restrict__ tmpb)
{
  __shared__ alignas(16) unsigned q_pk[2][8][32];      // 2 KB packed q (d-pairs)
  __shared__ alignas(16) unsigned char pt_raw[8448];   // p (bf16) then t8 (h-pairs)
  __shared__ alignas(16) float nacc_s[2][512];         // 4 KB PV result
  __shared__ alignas(16) unsigned rw_pk[32][8];        // 1 KB rw e-pairs [ep][h]
  __shared__ alignas(16) unsigned ew_pk[64][4];        // 1 KB ew h-pairs [e][hp]
  __shared__ alignas(16) float eb_s[64];
  __shared__ alignas(16) float pl2[2][64];
  __shared__ alignas(16) float inv_s[2][8];            // 1/sum

  unsigned short (*p_sb)[8][264] = (unsigned short (*)[8][264])pt_raw; // [r][h][y]
  unsigned (*t8_pk)[4][264] = (unsigned (*)[4][264])pt_raw;            // [r][hp][y]

  const int t = threadIdx.x;
  const int lane = t & 63;
  const int wv = t >> 6;
  const int b = blockIdx.x >> 7;
  const int x0 = (blockIdx.x & 127) * 2;
  const int y = t;

  // ---- phase 1: stage q packed, rw/ew pairs, eb
  {
    int r = t >> 7, h = (t >> 4) & 7, d0 = (t & 15) * 4;
    uint2 u = *(const uint2*)&qb[((size_t)(b*8 + h)*256 + x0 + r)*64 + d0];
    q_pk[r][h][(d0 >> 1)]     = u.x;
    q_pk[r][h][(d0 >> 1) + 1] = u.y;
  }
  { int epx = t >> 3, h = t & 7;
    rw_pk[epx][h] = pk2(rw[h*64 + 2*epx], rw[h*64 + 2*epx + 1]); }
  { int e = t >> 2, hp = t & 3;
    ew_pk[e][hp] = pk2(ew[(size_t)e*8 + 2*hp], ew[(size_t)e*8 + 2*hp + 1]); }
  if (t < 64) eb_s[t] = eb[t];
  const float madd0 = mask[(size_t)b*65536 + (size_t)x0*256 + y]       ? -1e30f : 0.f;
  const float madd1 = mask[(size_t)b*65536 + (size_t)x0*256 + 256 + y] ? -1e30f : 0.f;
  __syncthreads();

  // ---- phase 2a: edge bias (NT stream, e-pairs -> dot2)
  float acc[2][8];
  #pragma unroll
  for (int h = 0; h < 8; h++) { float rv = rb[h]; acc[0][h] = rv; acc[1][h] = rv; }
  {
    const float* ep = edge + (size_t)b*(64*65536) + (size_t)x0*256 + y;
    #pragma unroll 4
    for (int e2 = 0; e2 < 32; e2++) {
      float a0 = __builtin_nontemporal_load(ep + (size_t)(2*e2)*65536);
      float a1 = __builtin_nontemporal_load(ep + (size_t)(2*e2)*65536 + 256);
      float b0 = __builtin_nontemporal_load(ep + (size_t)(2*e2+1)*65536);
      float b1 = __builtin_nontemporal_load(ep + (size_t)(2*e2+1)*65536 + 256);
      unsigned v0p = pk2(a0, b0);   // row 0: pair (e, e+1)
      unsigned v1p = pk2(a1, b1);   // row 1
      uint4 w0 = *(const uint4*)&rw_pk[e2][0];
      uint4 w1 = *(const uint4*)&rw_pk[e2][4];
      acc[0][0] = dot2b(v0p, w0.x, acc[0][0]);
      acc[0][1] = dot2b(v0p, w0.y, acc[0][1]);
      acc[0][2] = dot2b(v0p, w0.z, acc[0][2]);
      acc[0][3] = dot2b(v0p, w0.w, acc[0][3]);
      acc[0][4] = dot2b(v0p, w1.x, acc[0][4]);
      acc[0][5] = dot2b(v0p, w1.y, acc[0][5]);
      acc[0][6] = dot2b(v0p, w1.z, acc[0][6]);
      acc[0][7] = dot2b(v0p, w1.w, acc[0][7]);
      acc[1][0] = dot2b(v1p, w0.x, acc[1][0]);
      acc[1][1] = dot2b(v1p, w0.y, acc[1][1]);
      acc[1][2] = dot2b(v1p, w0.z, acc[1][2]);
      acc[1][3] = dot2b(v1p, w0.w, acc[1][3]);
      acc[1][4] = dot2b(v1p, w1.x, acc[1][4]);
      acc[1][5] = dot2b(v1p, w1.y, acc[1][5]);
      acc[1][6] = dot2b(v1p, w1.z, acc[1][6]);
      acc[1][7] = dot2b(v1p, w1.w, acc[1][7]);
    }
  }

  // ---- phase 2b: QK^T (packed k x packed q -> dot2)
  #pragma unroll 2
  for (int h = 0; h < 8; h++) {
    const uint2* kq = ktq + (size_t)(b*8 + h)*4096 + y;
    float qk0 = 0.f, qk1 = 0.f;
    #pragma unroll
    for (int d4 = 0; d4 < 16; d4++) {
      uint2 k = kq[(size_t)d4*256];
      uint2 qa = *(const uint2*)&q_pk[0][h][d4*2];
      uint2 qc = *(const uint2*)&q_pk[1][h][d4*2];
      qk0 = dot2b(k.x, qa.x, qk0);
      qk0 = dot2b(k.y, qa.y, qk0);
      qk1 = dot2b(k.x, qc.x, qk1);
      qk1 = dot2b(k.y, qc.y, qk1);
    }
    acc[0][h] += SCALE_ * qk0;
    acc[1][h] += SCALE_ * qk1;
  }

  // ---- phase 3: p = exp(s + mask) -> bf16 LDS (p kept f32 in regs)
  float p[2][8];
  #pragma unroll
  for (int h = 0; h < 8; h++) {
    p[0][h] = __expf(acc[0][h] + madd0);
    p[1][h] = __expf(acc[1][h] + madd1);
    p_sb[0][h][y] = bf16b(p[0][h]);
    p_sb[1][h][y] = bf16b(p[1][h]);
  }
  __syncthreads();

  // ---- phase 4: PV via dot2 (v y-pairs x p y-pairs); psum via dot2 w/ ones
  {
    const int h = t >> 5;
    const int i2 = t & 31;
    const int d0 = i2 * 2;
    const unsigned ONES = 0x3F803F80u;   // bf16 {1.0, 1.0}
    const uint4* vp4 = (const uint4*)(vq + (size_t)(b*8 + h)*4096);
    float a00 = 0.f, a01 = 0.f, a10 = 0.f, a11 = 0.f;
    float ps0 = 0.f, ps1 = 0.f;
    #pragma unroll 4
    for (int y4 = 0; y4 < 64; y4++) {
      uint2 pp0 = *(const uint2*)&p_sb[0][h][y4*4];
      uint2 pp1 = *(const uint2*)&p_sb[1][h][y4*4];
      uint4 u = vp4[(size_t)y4*32 + i2];
      a00 = dot2b(pp0.x, u.x, a00); a00 = dot2b(pp0.y, u.y, a00);
      a01 = dot2b(pp0.x, u.z, a01); a01 = dot2b(pp0.y, u.w, a01);
      a10 = dot2b(pp1.x, u.x, a10); a10 = dot2b(pp1.y, u.y, a10);
      a11 = dot2b(pp1.x, u.z, a11); a11 = dot2b(pp1.y, u.w, a11);
      ps0 = dot2b(pp0.x, ONES, ps0); ps0 = dot2b(pp0.y, ONES, ps0);
      ps1 = dot2b(pp1.x, ONES, ps1); ps1 = dot2b(pp1.y, ONES, ps1);
    }
    float inv0 = 1.0f / ps0, inv1 = 1.0f / ps1;
    *(float2*)&nacc_s[0][h*64 + d0] = make_float2(a00*inv0, a01*inv0);
    *(float2*)&nacc_s[1][h*64 + d0] = make_float2(a10*inv1, a11*inv1);
    if (i2 == 0) { inv_s[0][h] = inv0; inv_s[1][h] = inv1; }
  }
  __syncthreads();   // p_sb fully consumed; nacc + inv ready

  // ---- phase 4.5: t8 = attn_sm + residual -> packed h-pairs (aliases p_sb)
  #pragma unroll
  for (int r = 0; r < 2; r++) {
    float v[8];
    #pragma unroll
    for (int h = 0; h < 8; h++) v[h] = p[r][h]*inv_s[r][h] + acc[r][h];
    t8_pk[r][0][y] = pk2(v[0], v[1]);
    t8_pk[r][1][y] = pk2(v[2], v[3]);
    t8_pk[r][2][y] = pk2(v[4], v[5]);
    t8_pk[r][3][y] = pk2(v[6], v[7]);
  }
  __syncthreads();

  // ---- phase 5: expand via dot2 + NT edge_out write + DPP pooling
  {
    const int r = wv & 1;
    const int epar = wv >> 1;
    const int y0 = lane * 4;
    const int xg = x0 + r;
    uint4 tfq[4];
    #pragma unroll
    for (int hp = 0; hp < 4; hp++) tfq[hp] = *(const uint4*)&t8_pk[r][hp][y0];
    uchar4 mb = *(const uchar4*)&mask[(size_t)b*65536 + (size_t)xg*256 + y0];
    const float md0 = mb.x ? -1e30f : 0.f;
    const float md1 = mb.y ? -1e30f : 0.f;
    const float md2 = mb.z ? -1e30f : 0.f;
    const float md3 = mb.w ? -1e30f : 0.f;
    for (int ec = 0; ec < 32; ec++) {
      int e = ec*2 + epar;
      uint4 w = *(const uint4*)&ew_pk[e][0];
      float ebv = eb_s[e];
      float eo0 = dot2b(tfq[3].x, w.w, dot2b(tfq[2].x, w.z,
                  dot2b(tfq[1].x, w.y, dot2b(tfq[0].x, w.x, ebv))));
      float eo1 = dot2b(tfq[3].y, w.w, dot2b(tfq[2].y, w.z,
                  dot2b(tfq[1].y, w.y, dot2b(tfq[0].y, w.x, ebv))));
      float eo2 = dot2b(tfq[3].z, w.w, dot2b(tfq[2].z, w.z,
                  dot2b(tfq[1].z, w.y, dot2b(tfq[0].z, w.x, ebv))));
      float eo3 = dot2b(tfq[3].w, w.w, dot2b(tfq[2].w, w.z,
                  dot2b(tfq[1].w, w.y, dot2b(tfq[0].w, w.x, ebv))));
      float e0v = __expf(eo0+md0), e1v = __expf(eo1+md1);
      float e2v = __expf(eo2+md2), e3v = __expf(eo3+md3);
      float se  = (e0v + e1v) + (e2v + e3v);
      float swe = (e0v*eo0 + e1v*eo1) + (e2v*eo2 + e3v*eo3);
      se  = wave_sum64(se);
      swe = wave_sum64(swe);
      if (lane == 0) pl2[r][e] = swe / se;
      f4_ ov = {eo0, eo1, eo2, eo3};
      __builtin_nontemporal_store(ov,
        (f4_*)&out_edge[((size_t)(b*64 + e)*256 + xg)*256 + y0]);
    }
  }
  __syncthreads();

  // ---- phase 6: node_tmp = PV + pool @ fc_w^T + fc_b  (bf16 out)
  #pragma unroll
  for (int pass = 0; pass < 2; pass++) {
    int cdx = t + pass*256;
    float bias_c = fcb[cdx];
    float a0 = nacc_s[0][cdx] + bias_c;
    float a1 = nacc_s[1][cdx] + bias_c;
    const float4* fw4 = (const float4*)fcw;
    #pragma unroll 4
    for (int e4 = 0; e4 < 16; e4++) {
      float4 pl0 = *(const float4*)&pl2[0][e4*4];
      float4 pl1 = *(const float4*)&pl2[1][e4*4];
      float4 f = fw4[(size_t)cdx*16 + e4];
      a0 += pl0.x*f.x + pl0.y*f.y + pl0.z*f.z + pl0.w*f.w;
      a1 += pl1.x*f.x + pl1.y*f.y + pl1.z*f.z + pl1.w*f.w;
    }
    tmpb[((size_t)b*256 + x0    )*512 + cdx] = bf16b(a0);
    tmpb[((size_t)b*256 + x0 + 1)*512 + cdx] = bf16b(a1);
  }
}

// ------- Kernel 3: output projection GEMM + bias (bf16 dot2, bf16 in) -------
__global__ __launch_bounds__(256) void proj_gemm(
    const unsigned short* __restrict__ Xb, const float* __restrict__ W,
    const float* __restrict__ bias, float* __restrict__ out)
{
  __shared__ alignas(16) unsigned A_pk[8][132];   // [kpair][row] packed bf16
  __shared__ alignas(16) unsigned W_pk[8][68];    // [kpair][col]
  const int t  = threadIdx.x;
  const int m0 = blockIdx.x * 128;
  const int o0 = blockIdx.y * 64;
  const int tm = (t & 15) * 8;
  const int to = (t >> 4) * 4;
  float acc[8][4];
  #pragma unroll
  for (int i = 0; i < 8; i++)
    #pragma unroll
    for (int j = 0; j < 4; j++) acc[i][j] = 0.f;

  const uint4* X4 = (const uint4*)Xb;   // row = 64 uint4 (512 bf16, c-pairs)
  const float4* W4 = (const float4*)W;
  for (int c0 = 0; c0 < 512; c0 += 16) {
    {
      int row = t >> 1, half = t & 1;   // uint4 = 8 bf16 = 4 c-pairs
      uint4 a = X4[(size_t)(m0 + row) * 64 + (c0 >> 3) + half];
      A_pk[half*4 + 0][row] = a.x;
      A_pk[half*4 + 1][row] = a.y;
      A_pk[half*4 + 2][row] = a.z;
      A_pk[half*4 + 3][row] = a.w;
    }
    {
      int row = t >> 2, quad = t & 3;
      float4 w = W4[(size_t)(o0 + row) * 128 + (c0 >> 2) + quad];
      W_pk[quad*2    ][row] = pk2(w.x, w.y);
      W_pk[quad*2 + 1][row] = pk2(w.z, w.w);
    }
    __syncthreads();
    #pragma unroll
    for (int kp = 0; kp < 8; kp++) {
      uint4 a0 = *(const uint4*)&A_pk[kp][tm];
      uint4 a1 = *(const uint4*)&A_pk[kp][tm + 4];
      uint4 w0 = *(const uint4*)&W_pk[kp][to];
      unsigned am[8] = {a0.x,a0.y,a0.z,a0.w,a1.x,a1.y,a1.z,a1.w};
      unsigned wn[4] = {w0.x,w0.y,w0.z,w0.w};
      #pragma unroll
      for (int i = 0; i < 8; i++)
        #pragma unroll
        for (int j = 0; j < 4; j++) acc[i][j] = dot2b(am[i], wn[j], acc[i][j]);
    }
    __syncthreads();
  }
  float4 bb = *(const float4*)&bias[o0 + to];
  #pragma unroll
  for (int i = 0; i < 8; i++) {
    int m = m0 + tm + i;
    float4 r = make_float4(acc[i][0]+bb.x, acc[i][1]+bb.y, acc[i][2]+bb.z, acc[i][3]+bb.w);
    *(float4*)&out[(size_t)m*512 + o0 + to] = r;
  }
}

extern "C" void kernel_launch(void* const* d_in, const int* in_sizes, int n_in,
                              void* d_out, int out_size, void* d_ws, size_t ws_size,
                              hipStream_t stream)
{
  (void)in_sizes; (void)n_in; (void)out_size; (void)ws_size;
  const float* node   = (const float*)d_in[0];
  const float* edge   = (const float*)d_in[1];
  const unsigned char* mask = (const unsigned char*)d_in[2];
  const float* qkv_w  = (const float*)d_in[3];
  const float* proj_w = (const float*)d_in[4];
  const float* proj_b = (const float*)d_in[5];
  const float* rw     = (const float*)d_in[6];
  const float* rb     = (const float*)d_in[7];
  const float* ew     = (const float*)d_in[8];
  const float* eb     = (const float*)d_in[9];
  const float* fcw    = (const float*)d_in[10];
  const float* fcb    = (const float*)d_in[11];

  float* out_node = (float*)d_out;
  float* out_edge = out_node + (size_t)16*256*512;

  char* ws = (char*)d_ws;
  unsigned short* qb  = (unsigned short*)(ws);                    // 4 MB
  uint2*          ktq = (uint2*)         (ws + (size_t)4*1024*1024);
  uint2*          vq  = (uint2*)         (ws + (size_t)8*1024*1024);
  unsigned short* tmpb= (unsigned short*)(ws + (size_t)12*1024*1024);

  qkv_gemm <<<dim3(32, 24, 1), 256, 0, stream>>>(node, qkv_w, qb, ktq, vq);
  fused_attn<<<dim3(2048, 1, 1), 256, 0, stream>>>(qb, ktq, vq, edge, mask,
                                                   rw, rb, ew, eb, fcw, fcb,
                                                   out_edge, tmpb);
  proj_gemm<<<dim3(32, 8, 1), 256, 0, stream>>>(tmpb, proj_w, proj_b, out_node);
}

// Round 13
// 246.102 us; speedup vs baseline: 1.9266x; 1.0370x over previous
//
#include <hip/hip_runtime.h>
#include <hip/hip_bf16.h>
#include <cstdint>
#include <cstddef>

#define SCALE_ 0.125f
// B=16 N=256 C=512 H=8 HD=64 E=64

typedef float f4_ __attribute__((ext_vector_type(4)));
typedef __bf16 bf2_ __attribute__((ext_vector_type(2)));

__device__ __forceinline__ unsigned pk2(float a, float b) {
  union { __hip_bfloat16 h[2]; unsigned u; } x;
  x.h[0] = __float2bfloat16(a);
  x.h[1] = __float2bfloat16(b);
  return x.u;
}
__device__ __forceinline__ unsigned short bf16b(float a) {
  union { __hip_bfloat16 h; unsigned short s; } x;
  x.h = __float2bfloat16(a);
  return x.s;
}
__device__ __forceinline__ float blo(unsigned u) { return __uint_as_float(u << 16); }
__device__ __forceinline__ float bhi(unsigned u) { return __uint_as_float(u & 0xffff0000u); }

// packed bf16 pair dot: d = a.lo*b.lo + a.hi*b.hi + c  (one VALU op on gfx950)
__device__ __forceinline__ float dot2b(unsigned a, unsigned b, float c) {
#if __has_builtin(__builtin_amdgcn_fdot2_f32_bf16)
  return __builtin_amdgcn_fdot2_f32_bf16(__builtin_bit_cast(bf2_, a),
                                         __builtin_bit_cast(bf2_, b), c, false);
#else
  return fmaf(blo(a), blo(b), fmaf(bhi(a), bhi(b), c));
#endif
}

template<int CTRL, int RM>
__device__ __forceinline__ float dppadd(float v) {
  int x = __builtin_amdgcn_update_dpp(0, __float_as_int(v), CTRL, RM, 0xf, true);
  return v + __int_as_float(x);
}
__device__ __forceinline__ float wave_sum64(float v) {
  v = dppadd<0x111, 0xf>(v);   // row_shr:1
  v = dppadd<0x112, 0xf>(v);   // row_shr:2
  v = dppadd<0x114, 0xf>(v);   // row_shr:4
  v = dppadd<0x118, 0xf>(v);   // row_shr:8
  v = dppadd<0x142, 0xa>(v);   // row_bcast:15 -> rows 1,3
  v = dppadd<0x143, 0xc>(v);   // row_bcast:31 -> rows 2,3
  return __int_as_float(__builtin_amdgcn_readlane(__float_as_int(v), 63));
}

// ------- Kernel 1: QKV projection GEMM (bf16 dot2, f32 in, bf16 out) --------
__global__ __launch_bounds__(256) void qkv_gemm(
    const float* __restrict__ X, const float* __restrict__ W,
    unsigned short* __restrict__ qb, uint2* __restrict__ ktq, uint2* __restrict__ vq)
{
  __shared__ alignas(16) unsigned A_pk[8][132];   // [kpair][row] packed bf16
  __shared__ alignas(16) unsigned W_pk[8][68];    // [kpair][col]
  const int t  = threadIdx.x;
  const int m0 = blockIdx.x * 128;
  const int o0 = blockIdx.y * 64;
  const int tm = (t & 15) * 8;
  const int to = (t >> 4) * 4;
  float acc[8][4];
  #pragma unroll
  for (int i = 0; i < 8; i++)
    #pragma unroll
    for (int j = 0; j < 4; j++) acc[i][j] = 0.f;

  const float4* X4 = (const float4*)X;
  const float4* W4 = (const float4*)W;
  for (int c0 = 0; c0 < 512; c0 += 16) {
    #pragma unroll
    for (int i = 0; i < 2; i++) {
      int id = t + 256 * i;
      int row = id >> 2, quad = id & 3;
      float4 a = X4[(size_t)(m0 + row) * 128 + (c0 >> 2) + quad];
      A_pk[quad*2    ][row] = pk2(a.x, a.y);
      A_pk[quad*2 + 1][row] = pk2(a.z, a.w);
    }
    {
      int row = t >> 2, quad = t & 3;
      float4 w = W4[(size_t)(o0 + row) * 128 + (c0 >> 2) + quad];
      W_pk[quad*2    ][row] = pk2(w.x, w.y);
      W_pk[quad*2 + 1][row] = pk2(w.z, w.w);
    }
    __syncthreads();
    #pragma unroll
    for (int kp = 0; kp < 8; kp++) {
      uint4 a0 = *(const uint4*)&A_pk[kp][tm];
      uint4 a1 = *(const uint4*)&A_pk[kp][tm + 4];
      uint4 w0 = *(const uint4*)&W_pk[kp][to];
      unsigned am[8] = {a0.x,a0.y,a0.z,a0.w,a1.x,a1.y,a1.z,a1.w};
      unsigned wn[4] = {w0.x,w0.y,w0.z,w0.w};
      #pragma unroll
      for (int i = 0; i < 8; i++)
        #pragma unroll
        for (int j = 0; j < 4; j++) acc[i][j] = dot2b(am[i], wn[j], acc[i][j]);
    }
    __syncthreads();
  }
  const int three = o0 >> 9;
  const int h = (o0 >> 6) & 7;
  if (three == 0) {
    #pragma unroll
    for (int i = 0; i < 8; i++) {
      int m = m0 + tm + i;
      int b = m >> 8, n = m & 255;
      unsigned u0 = pk2(acc[i][0], acc[i][1]);
      unsigned u1 = pk2(acc[i][2], acc[i][3]);
      *(uint2*)&qb[((size_t)(b*8 + h)*256 + n)*64 + to] = make_uint2(u0, u1);
    }
  } else if (three == 1) {
    #pragma unroll
    for (int i = 0; i < 8; i++) {
      int m = m0 + tm + i;
      int b = m >> 8, n = m & 255;
      ktq[(size_t)(b*8 + h)*4096 + (size_t)(to >> 2)*256 + n] =
        make_uint2(pk2(acc[i][0], acc[i][1]), pk2(acc[i][2], acc[i][3]));
    }
  } else {
    int m = m0 + tm;
    int b = m >> 8, n0 = m & 255;
    #pragma unroll
    for (int ii = 0; ii < 2; ii++) {
      #pragma unroll
      for (int j = 0; j < 4; j++) {
        vq[(size_t)(b*8 + h)*4096 + (size_t)((n0 >> 2) + ii)*64 + to + j] =
          make_uint2(pk2(acc[4*ii+0][j], acc[4*ii+1][j]),
                     pk2(acc[4*ii+2][j], acc[4*ii+3][j]));
      }
    }
  }
}

// -------- Kernel 2: fused attn + edge pipeline (4 rows/block, 256t) ---------
// K/V/fcw loads shared across 4 rows (halves/quarters L2 traffic vs 2-row).
__global__ __launch_bounds__(256) void fused_attn(
    const unsigned short* __restrict__ qb, const uint2* __restrict__ ktq,
    const uint2* __restrict__ vq,
    const float* __restrict__ edge, const unsigned char* __restrict__ mask,
    const float* __restrict__ rw, const float* __restrict__ rb,
    const float* __restrict__ ew, const float* __restrict__ eb,
    const float* __restrict__ fcw, const float* __restrict__ fcb,
    float* __restrict__ out_edge, unsigned short* __restrict__ tmpb)
{
  __shared__ alignas(16) unsigned q_pk[4][8][32];      // 4 KB packed q (d-pairs)
  __shared__ alignas(16) unsigned char pt_raw[16896];  // p (bf16) then t8 (h-pairs)
  __shared__ alignas(16) float nacc_s[4][512];         // 8 KB PV result
  __shared__ alignas(16) unsigned rw_pk[32][8];        // 1 KB rw e-pairs [ep][h]
  __shared__ alignas(16) unsigned ew_pk[64][4];        // 1 KB ew h-pairs [e][hp]
  __shared__ alignas(16) float eb_s[64];
  __shared__ alignas(16) float pl2[4][64];             // 1 KB
  __shared__ alignas(16) float inv_s[4][8];            // 1/sum

  unsigned short (*p_sb)[8][264] = (unsigned short (*)[8][264])pt_raw; // [r][h][y]
  unsigned (*t8_pk)[4][264] = (unsigned (*)[4][264])pt_raw;            // [r][hp][y]

  const int t = threadIdx.x;
  const int lane = t & 63;
  const int wv = t >> 6;
  const int b = blockIdx.x >> 6;
  const int x0 = (blockIdx.x & 63) * 4;
  const int y = t;

  // ---- phase 1: stage q packed (4 rows), rw/ew pairs, eb, mask
  #pragma unroll
  for (int i = 0; i < 4; i++) {
    int id = t + i*256;                 // 1024 uints
    int r = id >> 8, rest = id & 255;
    int h = rest >> 5, d2 = rest & 31;
    q_pk[r][h][d2] =
      *(const unsigned*)&qb[((size_t)(b*8 + h)*256 + x0 + r)*64 + d2*2];
  }
  { int epx = t >> 3, h = t & 7;
    rw_pk[epx][h] = pk2(rw[h*64 + 2*epx], rw[h*64 + 2*epx + 1]); }
  { int e = t >> 2, hp = t & 3;
    ew_pk[e][hp] = pk2(ew[(size_t)e*8 + 2*hp], ew[(size_t)e*8 + 2*hp + 1]); }
  if (t < 64) eb_s[t] = eb[t];
  float madd[4];
  #pragma unroll
  for (int r = 0; r < 4; r++)
    madd[r] = mask[(size_t)b*65536 + (size_t)(x0 + r)*256 + y] ? -1e30f : 0.f;
  __syncthreads();

  // ---- phase 2a: edge bias (NT stream, e-pairs -> dot2, 4 rows)
  float acc[4][8];
  #pragma unroll
  for (int h = 0; h < 8; h++) {
    float rv = rb[h];
    #pragma unroll
    for (int r = 0; r < 4; r++) acc[r][h] = rv;
  }
  {
    const float* ep = edge + (size_t)b*(64*65536) + (size_t)x0*256 + y;
    #pragma unroll 4
    for (int e2 = 0; e2 < 32; e2++) {
      unsigned vp[4];
      #pragma unroll
      for (int r = 0; r < 4; r++) {
        float a = __builtin_nontemporal_load(ep + (size_t)(2*e2)*65536 + r*256);
        float c = __builtin_nontemporal_load(ep + (size_t)(2*e2+1)*65536 + r*256);
        vp[r] = pk2(a, c);
      }
      uint4 w0 = *(const uint4*)&rw_pk[e2][0];
      uint4 w1 = *(const uint4*)&rw_pk[e2][4];
      unsigned wh[8] = {w0.x,w0.y,w0.z,w0.w,w1.x,w1.y,w1.z,w1.w};
      #pragma unroll
      for (int r = 0; r < 4; r++)
        #pragma unroll
        for (int h = 0; h < 8; h++)
          acc[r][h] = dot2b(vp[r], wh[h], acc[r][h]);
    }
  }

  // ---- phase 2b: QK^T (k loads shared across 4 rows)
  #pragma unroll 2
  for (int h = 0; h < 8; h++) {
    const uint2* kq = ktq + (size_t)(b*8 + h)*4096 + y;
    float qk[4] = {0.f, 0.f, 0.f, 0.f};
    #pragma unroll
    for (int d4 = 0; d4 < 16; d4++) {
      uint2 k = kq[(size_t)d4*256];
      #pragma unroll
      for (int r = 0; r < 4; r++) {
        uint2 qa = *(const uint2*)&q_pk[r][h][d4*2];
        qk[r] = dot2b(k.x, qa.x, qk[r]);
        qk[r] = dot2b(k.y, qa.y, qk[r]);
      }
    }
    #pragma unroll
    for (int r = 0; r < 4; r++) acc[r][h] += SCALE_ * qk[r];
  }

  // ---- phase 3: p = exp(s + mask) -> bf16 LDS
  #pragma unroll
  for (int r = 0; r < 4; r++)
    #pragma unroll
    for (int h = 0; h < 8; h++)
      p_sb[r][h][y] = bf16b(__expf(acc[r][h] + madd[r]));
  __syncthreads();

  // ---- phase 4: PV via dot2; v loads shared across 4 rows
  {
    const int h = t >> 5;
    const int i2 = t & 31;
    const int d0 = i2 * 2;
    const unsigned ONES = 0x3F803F80u;   // bf16 {1.0, 1.0}
    const uint4* vp4 = (const uint4*)(vq + (size_t)(b*8 + h)*4096);
    float a[4][2], ps[4];
    #pragma unroll
    for (int r = 0; r < 4; r++) { a[r][0] = 0.f; a[r][1] = 0.f; ps[r] = 0.f; }
    #pragma unroll 2
    for (int y4 = 0; y4 < 64; y4++) {
      uint4 u = vp4[(size_t)y4*32 + i2];
      #pragma unroll
      for (int r = 0; r < 4; r++) {
        uint2 pp = *(const uint2*)&p_sb[r][h][y4*4];
        a[r][0] = dot2b(pp.x, u.x, a[r][0]); a[r][0] = dot2b(pp.y, u.y, a[r][0]);
        a[r][1] = dot2b(pp.x, u.z, a[r][1]); a[r][1] = dot2b(pp.y, u.w, a[r][1]);
        ps[r] = dot2b(pp.x, ONES, ps[r]);    ps[r] = dot2b(pp.y, ONES, ps[r]);
      }
    }
    #pragma unroll
    for (int r = 0; r < 4; r++) {
      float inv = 1.0f / ps[r];
      *(float2*)&nacc_s[r][h*64 + d0] = make_float2(a[r][0]*inv, a[r][1]*inv);
    }
    if (i2 == 0) {
      #pragma unroll
      for (int r = 0; r < 4; r++) inv_s[r][h] = 1.0f / ps[r];
    }
  }
  __syncthreads();   // p_sb fully consumed; nacc + inv ready

  // ---- phase 4.5: t8 = attn_sm + residual -> packed h-pairs (aliases p_sb)
  #pragma unroll
  for (int r = 0; r < 4; r++) {
    float v[8];
    #pragma unroll
    for (int h = 0; h < 8; h++)
      v[h] = __expf(acc[r][h] + madd[r]) * inv_s[r][h] + acc[r][h];
    t8_pk[r][0][y] = pk2(v[0], v[1]);
    t8_pk[r][1][y] = pk2(v[2], v[3]);
    t8_pk[r][2][y] = pk2(v[4], v[5]);
    t8_pk[r][3][y] = pk2(v[6], v[7]);
  }
  __syncthreads();

  // ---- phase 5: expand via dot2 + NT edge_out write + DPP pooling
  // wave wv <-> row r = wv; 64 e's per wave; lane <-> 4 y's
  {
    const int r = wv;
    const int y0 = lane * 4;
    const int xg = x0 + r;
    uint4 tfq[4];
    #pragma unroll
    for (int hp = 0; hp < 4; hp++) tfq[hp] = *(const uint4*)&t8_pk[r][hp][y0];
    uchar4 mb = *(const uchar4*)&mask[(size_t)b*65536 + (size_t)xg*256 + y0];
    const float md0 = mb.x ? -1e30f : 0.f;
    const float md1 = mb.y ? -1e30f : 0.f;
    const float md2 = mb.z ? -1e30f : 0.f;
    const float md3 = mb.w ? -1e30f : 0.f;
    for (int e = 0; e < 64; e++) {
      uint4 w = *(const uint4*)&ew_pk[e][0];
      float ebv = eb_s[e];
      float eo0 = dot2b(tfq[3].x, w.w, dot2b(tfq[2].x, w.z,
                  dot2b(tfq[1].x, w.y, dot2b(tfq[0].x, w.x, ebv))));
      float eo1 = dot2b(tfq[3].y, w.w, dot2b(tfq[2].y, w.z,
                  dot2b(tfq[1].y, w.y, dot2b(tfq[0].y, w.x, ebv))));
      float eo2 = dot2b(tfq[3].z, w.w, dot2b(tfq[2].z, w.z,
                  dot2b(tfq[1].z, w.y, dot2b(tfq[0].z, w.x, ebv))));
      float eo3 = dot2b(tfq[3].w, w.w, dot2b(tfq[2].w, w.z,
                  dot2b(tfq[1].w, w.y, dot2b(tfq[0].w, w.x, ebv))));
      float e0v = __expf(eo0+md0), e1v = __expf(eo1+md1);
      float e2v = __expf(eo2+md2), e3v = __expf(eo3+md3);
      float se  = (e0v + e1v) + (e2v + e3v);
      float swe = (e0v*eo0 + e1v*eo1) + (e2v*eo2 + e3v*eo3);
      se  = wave_sum64(se);
      swe = wave_sum64(swe);
      if (lane == 0) pl2[r][e] = swe / se;
      f4_ ov = {eo0, eo1, eo2, eo3};
      __builtin_nontemporal_store(ov,
        (f4_*)&out_edge[((size_t)(b*64 + e)*256 + xg)*256 + y0]);
    }
  }
  __syncthreads();

  // ---- phase 6: node_tmp = PV + pool @ fc_w^T + fc_b (fw shared x4 rows)
  #pragma unroll
  for (int pass = 0; pass < 2; pass++) {
    int cdx = t + pass*256;
    float bias_c = fcb[cdx];
    float a[4];
    #pragma unroll
    for (int r = 0; r < 4; r++) a[r] = nacc_s[r][cdx] + bias_c;
    const float4* fw4 = (const float4*)fcw;
    #pragma unroll 4
    for (int e4 = 0; e4 < 16; e4++) {
      float4 f = fw4[(size_t)cdx*16 + e4];
      #pragma unroll
      for (int r = 0; r < 4; r++) {
        float4 pl = *(const float4*)&pl2[r][e4*4];
        a[r] += pl.x*f.x + pl.y*f.y + pl.z*f.z + pl.w*f.w;
      }
    }
    #pragma unroll
    for (int r = 0; r < 4; r++)
      tmpb[((size_t)b*256 + x0 + r)*512 + cdx] = bf16b(a[r]);
  }
}

// ------- Kernel 3: output projection GEMM + bias (bf16 dot2, bf16 in) -------
__global__ __launch_bounds__(256) void proj_gemm(
    const unsigned short* __restrict__ Xb, const float* __restrict__ W,
    const float* __restrict__ bias, float* __restrict__ out)
{
  __shared__ alignas(16) unsigned A_pk[8][132];   // [kpair][row] packed bf16
  __shared__ alignas(16) unsigned W_pk[8][68];    // [kpair][col]
  const int t  = threadIdx.x;
  const int m0 = blockIdx.x * 128;
  const int o0 = blockIdx.y * 64;
  const int tm = (t & 15) * 8;
  const int to = (t >> 4) * 4;
  float acc[8][4];
  #pragma unroll
  for (int i = 0; i < 8; i++)
    #pragma unroll
    for (int j = 0; j < 4; j++) acc[i][j] = 0.f;

  const uint4* X4 = (const uint4*)Xb;   // row = 64 uint4 (512 bf16, c-pairs)
  const float4* W4 = (const float4*)W;
  for (int c0 = 0; c0 < 512; c0 += 16) {
    {
      int row = t >> 1, half = t & 1;   // uint4 = 8 bf16 = 4 c-pairs
      uint4 a = X4[(size_t)(m0 + row) * 64 + (c0 >> 3) + half];
      A_pk[half*4 + 0][row] = a.x;
      A_pk[half*4 + 1][row] = a.y;
      A_pk[half*4 + 2][row] = a.z;
      A_pk[half*4 + 3][row] = a.w;
    }
    {
      int row = t >> 2, quad = t & 3;
      float4 w = W4[(size_t)(o0 + row) * 128 + (c0 >> 2) + quad];
      W_pk[quad*2    ][row] = pk2(w.x, w.y);
      W_pk[quad*2 + 1][row] = pk2(w.z, w.w);
    }
    __syncthreads();
    #pragma unroll
    for (int kp = 0; kp < 8; kp++) {
      uint4 a0 = *(const uint4*)&A_pk[kp][tm];
      uint4 a1 = *(const uint4*)&A_pk[kp][tm + 4];
      uint4 w0 = *(const uint4*)&W_pk[kp][to];
      unsigned am[8] = {a0.x,a0.y,a0.z,a0.w,a1.x,a1.y,a1.z,a1.w};
      unsigned wn[4] = {w0.x,w0.y,w0.z,w0.w};
      #pragma unroll
      for (int i = 0; i < 8; i++)
        #pragma unroll
        for (int j = 0; j < 4; j++) acc[i][j] = dot2b(am[i], wn[j], acc[i][j]);
    }
    __syncthreads();
  }
  float4 bb = *(const float4*)&bias[o0 + to];
  #pragma unroll
  for (int i = 0; i < 8; i++) {
    int m = m0 + tm + i;
    float4 r = make_float4(acc[i][0]+bb.x, acc[i][1]+bb.y, acc[i][2]+bb.z, acc[i][3]+bb.w);
    *(float4*)&out[(size_t)m*512 + o0 + to] = r;
  }
}

extern "C" void kernel_launch(void* const* d_in, const int* in_sizes, int n_in,
                              void* d_out, int out_size, void* d_ws, size_t ws_size,
                              hipStream_t stream)
{
  (void)in_sizes; (void)n_in; (void)out_size; (void)ws_size;
  const float* node   = (const float*)d_in[0];
  const float* edge   = (const float*)d_in[1];
  const unsigned char* mask = (const unsigned char*)d_in[2];
  const float* qkv_w  = (const float*)d_in[3];
  const float* proj_w = (const float*)d_in[4];
  const float* proj_b = (const float*)d_in[5];
  const float* rw     = (const float*)d_in[6];
  const float* rb     = (const float*)d_in[7];
  const float* ew     = (const float*)d_in[8];
  const float* eb     = (const float*)d_in[9];
  const float* fcw    = (const float*)d_in[10];
  const float* fcb    = (const float*)d_in[11];

  float* out_node = (float*)d_out;
  float* out_edge = out_node + (size_t)16*256*512;

  char* ws = (char*)d_ws;
  unsigned short* qb  = (unsigned short*)(ws);                    // 4 MB
  uint2*          ktq = (uint2*)         (ws + (size_t)4*1024*1024);
  uint2*          vq  = (uint2*)         (ws + (size_t)8*1024*1024);
  unsigned short* tmpb= (unsigned short*)(ws + (size_t)12*1024*1024);

  qkv_gemm <<<dim3(32, 24, 1), 256, 0, stream>>>(node, qkv_w, qb, ktq, vq);
  fused_attn<<<dim3(1024, 1, 1), 256, 0, stream>>>(qb, ktq, vq, edge, mask,
                                                   rw, rb, ew, eb, fcw, fcb,
                                                   out_edge, tmpb);
  proj_gemm<<<dim3(32, 8, 1), 256, 0, stream>>>(tmpb, proj_w, proj_b, out_node);
}

// Round 14
// 195.787 us; speedup vs baseline: 2.4218x; 1.2570x over previous
//
#include <hip/hip_runtime.h>
#include <hip/hip_bf16.h>
#include <cstdint>
#include <cstddef>

#define SCALE_ 0.125f
// B=16 N=256 C=512 H=8 HD=64 E=64

typedef float f4_ __attribute__((ext_vector_type(4)));
typedef __bf16 bf2_ __attribute__((ext_vector_type(2)));
typedef short bf8f_ __attribute__((ext_vector_type(8)));   // MFMA A/B frag (8 bf16)
typedef float f32x4_ __attribute__((ext_vector_type(4)));  // MFMA C/D frag

__device__ __forceinline__ unsigned pk2(float a, float b) {
  union { __hip_bfloat16 h[2]; unsigned u; } x;
  x.h[0] = __float2bfloat16(a);
  x.h[1] = __float2bfloat16(b);
  return x.u;
}
__device__ __forceinline__ unsigned short bf16b(float a) {
  union { __hip_bfloat16 h; unsigned short s; } x;
  x.h = __float2bfloat16(a);
  return x.s;
}
__device__ __forceinline__ float blo(unsigned u) { return __uint_as_float(u << 16); }
__device__ __forceinline__ float bhi(unsigned u) { return __uint_as_float(u & 0xffff0000u); }
__device__ __forceinline__ float b2f(unsigned short s) { return __uint_as_float(((unsigned)s) << 16); }

// packed bf16 pair dot: d = a.lo*b.lo + a.hi*b.hi + c  (one VALU op on gfx950)
__device__ __forceinline__ float dot2b(unsigned a, unsigned b, float c) {
#if __has_builtin(__builtin_amdgcn_fdot2_f32_bf16)
  return __builtin_amdgcn_fdot2_f32_bf16(__builtin_bit_cast(bf2_, a),
                                         __builtin_bit_cast(bf2_, b), c, false);
#else
  return fmaf(blo(a), blo(b), fmaf(bhi(a), bhi(b), c));
#endif
}

template<int CTRL, int RM>
__device__ __forceinline__ float dppadd(float v) {
  int x = __builtin_amdgcn_update_dpp(0, __float_as_int(v), CTRL, RM, 0xf, true);
  return v + __int_as_float(x);
}
__device__ __forceinline__ float wave_sum64(float v) {
  v = dppadd<0x111, 0xf>(v);   // row_shr:1
  v = dppadd<0x112, 0xf>(v);   // row_shr:2
  v = dppadd<0x114, 0xf>(v);   // row_shr:4
  v = dppadd<0x118, 0xf>(v);   // row_shr:8
  v = dppadd<0x142, 0xa>(v);   // row_bcast:15 -> rows 1,3
  v = dppadd<0x143, 0xc>(v);   // row_bcast:31 -> rows 2,3
  return __int_as_float(__builtin_amdgcn_readlane(__float_as_int(v), 63));
}

// ------- Kernel 1: QKV projection GEMM via MFMA (bf16, f32 in, bf16 out) ----
// 128x64 tile, 4 waves; K-chunks of 64 staged in LDS as packed bf16 [dim][72].
// A frag: row=lane&15, k=(lane>>4)*8+j ; B frag: col=lane&15, same k.
// C/D: col=lane&15, row=(lane>>4)*4+reg (m89-verified). C goes through LDS so
// the q/kt/v scatter epilogue is the (validated) dot2-version code unchanged.
__global__ __launch_bounds__(256) void qkv_gemm(
    const float* __restrict__ X, const float* __restrict__ W,
    unsigned short* __restrict__ qb, uint2* __restrict__ ktq, uint2* __restrict__ vq)
{
  __shared__ alignas(16) unsigned ABbuf[128*36 + 64*36];   // A | B, 27 KB
  unsigned* A_pk = ABbuf;                  // [128 rows][36 uints] (72 bf16)
  unsigned* B_pk = ABbuf + 128*36;         // [64 cols][36 uints]
  unsigned short* A16 = (unsigned short*)A_pk;
  unsigned short* B16 = (unsigned short*)B_pk;
  unsigned short* C16 = (unsigned short*)ABbuf;  // reuse: [128][68] bf16

  const int t  = threadIdx.x;
  const int lane = t & 63;
  const int wv = t >> 6;
  const int m0 = blockIdx.x * 128;
  const int o0 = blockIdx.y * 64;
  const int wrow = wv * 32;

  f32x4_ acc[2][4];
  #pragma unroll
  for (int fm = 0; fm < 2; fm++)
    #pragma unroll
    for (int fn = 0; fn < 4; fn++) acc[fm][fn] = (f32x4_){0.f, 0.f, 0.f, 0.f};

  const float4* X4 = (const float4*)X;
  const float4* W4 = (const float4*)W;

  for (int cc = 0; cc < 512; cc += 64) {
    // stage A: 128 rows x 64 cols (16 float4/row -> 2048 float4)
    #pragma unroll
    for (int i = 0; i < 8; i++) {
      int id = t + 256*i;
      int row = id >> 4, c4 = id & 15;
      float4 a = X4[(size_t)(m0 + row)*128 + (cc >> 2) + c4];
      A_pk[row*36 + c4*2    ] = pk2(a.x, a.y);
      A_pk[row*36 + c4*2 + 1] = pk2(a.z, a.w);
    }
    // stage B: 64 rows (o) x 64 cols (c)
    #pragma unroll
    for (int i = 0; i < 4; i++) {
      int id = t + 256*i;
      int row = id >> 4, c4 = id & 15;
      float4 w = W4[(size_t)(o0 + row)*128 + (cc >> 2) + c4];
      B_pk[row*36 + c4*2    ] = pk2(w.x, w.y);
      B_pk[row*36 + c4*2 + 1] = pk2(w.z, w.w);
    }
    __syncthreads();
    #pragma unroll
    for (int ks = 0; ks < 64; ks += 32) {
      const int kb = ks + (lane >> 4)*8;
      bf8f_ af0 = *(const bf8f_*)&A16[(wrow      + (lane & 15))*72 + kb];
      bf8f_ af1 = *(const bf8f_*)&A16[(wrow + 16 + (lane & 15))*72 + kb];
      #pragma unroll
      for (int fn = 0; fn < 4; fn++) {
        bf8f_ bf = *(const bf8f_*)&B16[(fn*16 + (lane & 15))*72 + kb];
        acc[0][fn] = __builtin_amdgcn_mfma_f32_16x16x32_bf16(af0, bf, acc[0][fn], 0, 0, 0);
        acc[1][fn] = __builtin_amdgcn_mfma_f32_16x16x32_bf16(af1, bf, acc[1][fn], 0, 0, 0);
      }
    }
    __syncthreads();
  }

  // write acc -> C_lds (bf16), then scatter with the validated epilogue
  #pragma unroll
  for (int fm = 0; fm < 2; fm++)
    #pragma unroll
    for (int fn = 0; fn < 4; fn++)
      #pragma unroll
      for (int r = 0; r < 4; r++)
        C16[(wrow + fm*16 + (lane >> 4)*4 + r)*68 + fn*16 + (lane & 15)] =
          bf16b(acc[fm][fn][r]);
  __syncthreads();

  const int tm = (t & 15) * 8;
  const int to = (t >> 4) * 4;
  const int three = o0 >> 9;
  const int h = (o0 >> 6) & 7;
  if (three == 0) {
    #pragma unroll
    for (int i = 0; i < 8; i++) {
      int m = m0 + tm + i;
      int b = m >> 8, n = m & 255;
      uint2 u = *(const uint2*)&C16[(tm + i)*68 + to];
      *(uint2*)&qb[((size_t)(b*8 + h)*256 + n)*64 + to] = u;
    }
  } else if (three == 1) {
    #pragma unroll
    for (int i = 0; i < 8; i++) {
      int m = m0 + tm + i;
      int b = m >> 8, n = m & 255;
      uint2 u = *(const uint2*)&C16[(tm + i)*68 + to];
      ktq[(size_t)(b*8 + h)*4096 + (size_t)(to >> 2)*256 + n] = u;
    }
  } else {
    int m = m0 + tm;
    int b = m >> 8, n0 = m & 255;
    #pragma unroll
    for (int ii = 0; ii < 2; ii++) {
      #pragma unroll
      for (int j = 0; j < 4; j++) {
        unsigned ua = C16[(tm + 4*ii    )*68 + to + j];
        unsigned ub = C16[(tm + 4*ii + 1)*68 + to + j];
        unsigned uc = C16[(tm + 4*ii + 2)*68 + to + j];
        unsigned ud = C16[(tm + 4*ii + 3)*68 + to + j];
        vq[(size_t)(b*8 + h)*4096 + (size_t)((n0 >> 2) + ii)*64 + to + j] =
          make_uint2(ua | (ub << 16), uc | (ud << 16));
      }
    }
  }
}

// -------- Kernel 2: fused attn + edge pipeline (4 rows/block, 256t) ---------
// K/V/fcw loads shared across 4 rows; nacc in bf16 (LDS ~29 KB -> 5 blocks/CU)
__global__ __launch_bounds__(256) void fused_attn(
    const unsigned short* __restrict__ qb, const uint2* __restrict__ ktq,
    const uint2* __restrict__ vq,
    const float* __restrict__ edge, const unsigned char* __restrict__ mask,
    const float* __restrict__ rw, const float* __restrict__ rb,
    const float* __restrict__ ew, const float* __restrict__ eb,
    const float* __restrict__ fcw, const float* __restrict__ fcb,
    float* __restrict__ out_edge, unsigned short* __restrict__ tmpb)
{
  __shared__ alignas(16) unsigned q_pk[4][8][32];      // 4 KB packed q (d-pairs)
  __shared__ alignas(16) unsigned char pt_raw[16896];  // p (bf16) then t8 (h-pairs)
  __shared__ alignas(16) unsigned short nacc16[4][512];// 4 KB PV result (bf16)
  __shared__ alignas(16) unsigned rw_pk[32][8];        // 1 KB rw e-pairs [ep][h]
  __shared__ alignas(16) unsigned ew_pk[64][4];        // 1 KB ew h-pairs [e][hp]
  __shared__ alignas(16) float eb_s[64];
  __shared__ alignas(16) float pl2[4][64];             // 1 KB
  __shared__ alignas(16) float inv_s[4][8];            // 1/sum

  unsigned short (*p_sb)[8][264] = (unsigned short (*)[8][264])pt_raw; // [r][h][y]
  unsigned (*t8_pk)[4][264] = (unsigned (*)[4][264])pt_raw;            // [r][hp][y]

  const int t = threadIdx.x;
  const int lane = t & 63;
  const int wv = t >> 6;
  const int b = blockIdx.x >> 6;
  const int x0 = (blockIdx.x & 63) * 4;
  const int y = t;

  // ---- phase 1: stage q packed (4 rows), rw/ew pairs, eb, mask
  #pragma unroll
  for (int i = 0; i < 4; i++) {
    int id = t + i*256;                 // 1024 uints
    int r = id >> 8, rest = id & 255;
    int h = rest >> 5, d2 = rest & 31;
    q_pk[r][h][d2] =
      *(const unsigned*)&qb[((size_t)(b*8 + h)*256 + x0 + r)*64 + d2*2];
  }
  { int epx = t >> 3, h = t & 7;
    rw_pk[epx][h] = pk2(rw[h*64 + 2*epx], rw[h*64 + 2*epx + 1]); }
  { int e = t >> 2, hp = t & 3;
    ew_pk[e][hp] = pk2(ew[(size_t)e*8 + 2*hp], ew[(size_t)e*8 + 2*hp + 1]); }
  if (t < 64) eb_s[t] = eb[t];
  float madd[4];
  #pragma unroll
  for (int r = 0; r < 4; r++)
    madd[r] = mask[(size_t)b*65536 + (size_t)(x0 + r)*256 + y] ? -1e30f : 0.f;
  __syncthreads();

  // ---- phase 2a: edge bias (NT stream, e-pairs -> dot2, 4 rows)
  float acc[4][8];
  #pragma unroll
  for (int h = 0; h < 8; h++) {
    float rv = rb[h];
    #pragma unroll
    for (int r = 0; r < 4; r++) acc[r][h] = rv;
  }
  {
    const float* ep = edge + (size_t)b*(64*65536) + (size_t)x0*256 + y;
    #pragma unroll 4
    for (int e2 = 0; e2 < 32; e2++) {
      unsigned vp[4];
      #pragma unroll
      for (int r = 0; r < 4; r++) {
        float a = __builtin_nontemporal_load(ep + (size_t)(2*e2)*65536 + r*256);
        float c = __builtin_nontemporal_load(ep + (size_t)(2*e2+1)*65536 + r*256);
        vp[r] = pk2(a, c);
      }
      uint4 w0 = *(const uint4*)&rw_pk[e2][0];
      uint4 w1 = *(const uint4*)&rw_pk[e2][4];
      unsigned wh[8] = {w0.x,w0.y,w0.z,w0.w,w1.x,w1.y,w1.z,w1.w};
      #pragma unroll
      for (int r = 0; r < 4; r++)
        #pragma unroll
        for (int h = 0; h < 8; h++)
          acc[r][h] = dot2b(vp[r], wh[h], acc[r][h]);
    }
  }

  // ---- phase 2b: QK^T (k loads shared across 4 rows)
  #pragma unroll 2
  for (int h = 0; h < 8; h++) {
    const uint2* kq = ktq + (size_t)(b*8 + h)*4096 + y;
    float qk[4] = {0.f, 0.f, 0.f, 0.f};
    #pragma unroll
    for (int d4 = 0; d4 < 16; d4++) {
      uint2 k = kq[(size_t)d4*256];
      #pragma unroll
      for (int r = 0; r < 4; r++) {
        uint2 qa = *(const uint2*)&q_pk[r][h][d4*2];
        qk[r] = dot2b(k.x, qa.x, qk[r]);
        qk[r] = dot2b(k.y, qa.y, qk[r]);
      }
    }
    #pragma unroll
    for (int r = 0; r < 4; r++) acc[r][h] += SCALE_ * qk[r];
  }

  // ---- phase 3: p = exp(s + mask) -> bf16 LDS
  #pragma unroll
  for (int r = 0; r < 4; r++)
    #pragma unroll
    for (int h = 0; h < 8; h++)
      p_sb[r][h][y] = bf16b(__expf(acc[r][h] + madd[r]));
  __syncthreads();

  // ---- phase 4: PV via dot2; v loads shared across 4 rows
  {
    const int h = t >> 5;
    const int i2 = t & 31;
    const int d0 = i2 * 2;
    const unsigned ONES = 0x3F803F80u;   // bf16 {1.0, 1.0}
    const uint4* vp4 = (const uint4*)(vq + (size_t)(b*8 + h)*4096);
    float a[4][2], ps[4];
    #pragma unroll
    for (int r = 0; r < 4; r++) { a[r][0] = 0.f; a[r][1] = 0.f; ps[r] = 0.f; }
    #pragma unroll 2
    for (int y4 = 0; y4 < 64; y4++) {
      uint4 u = vp4[(size_t)y4*32 + i2];
      #pragma unroll
      for (int r = 0; r < 4; r++) {
        uint2 pp = *(const uint2*)&p_sb[r][h][y4*4];
        a[r][0] = dot2b(pp.x, u.x, a[r][0]); a[r][0] = dot2b(pp.y, u.y, a[r][0]);
        a[r][1] = dot2b(pp.x, u.z, a[r][1]); a[r][1] = dot2b(pp.y, u.w, a[r][1]);
        ps[r] = dot2b(pp.x, ONES, ps[r]);    ps[r] = dot2b(pp.y, ONES, ps[r]);
      }
    }
    #pragma unroll
    for (int r = 0; r < 4; r++) {
      float inv = 1.0f / ps[r];
      *(unsigned*)&nacc16[r][h*64 + d0] = pk2(a[r][0]*inv, a[r][1]*inv);
    }
    if (i2 == 0) {
      #pragma unroll
      for (int r = 0; r < 4; r++) inv_s[r][h] = 1.0f / ps[r];
    }
  }
  __syncthreads();   // p_sb fully consumed; nacc + inv ready

  // ---- phase 4.5: t8 = attn_sm + residual -> packed h-pairs (aliases p_sb)
  #pragma unroll
  for (int r = 0; r < 4; r++) {
    float v[8];
    #pragma unroll
    for (int h = 0; h < 8; h++)
      v[h] = __expf(acc[r][h] + madd[r]) * inv_s[r][h] + acc[r][h];
    t8_pk[r][0][y] = pk2(v[0], v[1]);
    t8_pk[r][1][y] = pk2(v[2], v[3]);
    t8_pk[r][2][y] = pk2(v[4], v[5]);
    t8_pk[r][3][y] = pk2(v[6], v[7]);
  }
  __syncthreads();

  // ---- phase 5: expand via dot2 + NT edge_out write + DPP pooling
  // wave wv <-> row r = wv; 64 e's per wave; lane <-> 4 y's
  {
    const int r = wv;
    const int y0 = lane * 4;
    const int xg = x0 + r;
    uint4 tfq[4];
    #pragma unroll
    for (int hp = 0; hp < 4; hp++) tfq[hp] = *(const uint4*)&t8_pk[r][hp][y0];
    uchar4 mb = *(const uchar4*)&mask[(size_t)b*65536 + (size_t)xg*256 + y0];
    const float md0 = mb.x ? -1e30f : 0.f;
    const float md1 = mb.y ? -1e30f : 0.f;
    const float md2 = mb.z ? -1e30f : 0.f;
    const float md3 = mb.w ? -1e30f : 0.f;
    for (int e = 0; e < 64; e++) {
      uint4 w = *(const uint4*)&ew_pk[e][0];
      float ebv = eb_s[e];
      float eo0 = dot2b(tfq[3].x, w.w, dot2b(tfq[2].x, w.z,
                  dot2b(tfq[1].x, w.y, dot2b(tfq[0].x, w.x, ebv))));
      float eo1 = dot2b(tfq[3].y, w.w, dot2b(tfq[2].y, w.z,
                  dot2b(tfq[1].y, w.y, dot2b(tfq[0].y, w.x, ebv))));
      float eo2 = dot2b(tfq[3].z, w.w, dot2b(tfq[2].z, w.z,
                  dot2b(tfq[1].z, w.y, dot2b(tfq[0].z, w.x, ebv))));
      float eo3 = dot2b(tfq[3].w, w.w, dot2b(tfq[2].w, w.z,
                  dot2b(tfq[1].w, w.y, dot2b(tfq[0].w, w.x, ebv))));
      float e0v = __expf(eo0+md0), e1v = __expf(eo1+md1);
      float e2v = __expf(eo2+md2), e3v = __expf(eo3+md3);
      float se  = (e0v + e1v) + (e2v + e3v);
      float swe = (e0v*eo0 + e1v*eo1) + (e2v*eo2 + e3v*eo3);
      se  = wave_sum64(se);
      swe = wave_sum64(swe);
      if (lane == 0) pl2[r][e] = swe / se;
      f4_ ov = {eo0, eo1, eo2, eo3};
      __builtin_nontemporal_store(ov,
        (f4_*)&out_edge[((size_t)(b*64 + e)*256 + xg)*256 + y0]);
    }
  }
  __syncthreads();

  // ---- phase 6: node_tmp = PV + pool @ fc_w^T + fc_b (fw shared x4 rows)
  #pragma unroll
  for (int pass = 0; pass < 2; pass++) {
    int cdx = t + pass*256;
    float bias_c = fcb[cdx];
    float a[4];
    #pragma unroll
    for (int r = 0; r < 4; r++) a[r] = b2f(nacc16[r][cdx]) + bias_c;
    const float4* fw4 = (const float4*)fcw;
    #pragma unroll 4
    for (int e4 = 0; e4 < 16; e4++) {
      float4 f = fw4[(size_t)cdx*16 + e4];
      #pragma unroll
      for (int r = 0; r < 4; r++) {
        float4 pl = *(const float4*)&pl2[r][e4*4];
        a[r] += pl.x*f.x + pl.y*f.y + pl.z*f.z + pl.w*f.w;
      }
    }
    #pragma unroll
    for (int r = 0; r < 4; r++)
      tmpb[((size_t)b*256 + x0 + r)*512 + cdx] = bf16b(a[r]);
  }
}

// ------- Kernel 3: output projection GEMM + bias (bf16 dot2, bf16 in) -------
__global__ __launch_bounds__(256) void proj_gemm(
    const unsigned short* __restrict__ Xb, const float* __restrict__ W,
    const float* __restrict__ bias, float* __restrict__ out)
{
  __shared__ alignas(16) unsigned A_pk[8][132];   // [kpair][row] packed bf16
  __shared__ alignas(16) unsigned W_pk[8][68];    // [kpair][col]
  const int t  = threadIdx.x;
  const int m0 = blockIdx.x * 128;
  const int o0 = blockIdx.y * 64;
  const int tm = (t & 15) * 8;
  const int to = (t >> 4) * 4;
  float acc[8][4];
  #pragma unroll
  for (int i = 0; i < 8; i++)
    #pragma unroll
    for (int j = 0; j < 4; j++) acc[i][j] = 0.f;

  const uint4* X4 = (const uint4*)Xb;   // row = 64 uint4 (512 bf16, c-pairs)
  const float4* W4 = (const float4*)W;
  for (int c0 = 0; c0 < 512; c0 += 16) {
    {
      int row = t >> 1, half = t & 1;   // uint4 = 8 bf16 = 4 c-pairs
      uint4 a = X4[(size_t)(m0 + row) * 64 + (c0 >> 3) + half];
      A_pk[half*4 + 0][row] = a.x;
      A_pk[half*4 + 1][row] = a.y;
      A_pk[half*4 + 2][row] = a.z;
      A_pk[half*4 + 3][row] = a.w;
    }
    {
      int row = t >> 2, quad = t & 3;
      float4 w = W4[(size_t)(o0 + row) * 128 + (c0 >> 2) + quad];
      W_pk[quad*2    ][row] = pk2(w.x, w.y);
      W_pk[quad*2 + 1][row] = pk2(w.z, w.w);
    }
    __syncthreads();
    #pragma unroll
    for (int kp = 0; kp < 8; kp++) {
      uint4 a0 = *(const uint4*)&A_pk[kp][tm];
      uint4 a1 = *(const uint4*)&A_pk[kp][tm + 4];
      uint4 w0 = *(const uint4*)&W_pk[kp][to];
      unsigned am[8] = {a0.x,a0.y,a0.z,a0.w,a1.x,a1.y,a1.z,a1.w};
      unsigned wn[4] = {w0.x,w0.y,w0.z,w0.w};
      #pragma unroll
      for (int i = 0; i < 8; i++)
        #pragma unroll
        for (int j = 0; j < 4; j++) acc[i][j] = dot2b(am[i], wn[j], acc[i][j]);
    }
    __syncthreads();
  }
  float4 bb = *(const float4*)&bias[o0 + to];
  #pragma unroll
  for (int i = 0; i < 8; i++) {
    int m = m0 + tm + i;
    float4 r = make_float4(acc[i][0]+bb.x, acc[i][1]+bb.y, acc[i][2]+bb.z, acc[i][3]+bb.w);
    *(float4*)&out[(size_t)m*512 + o0 + to] = r;
  }
}

extern "C" void kernel_launch(void* const* d_in, const int* in_sizes, int n_in,
                              void* d_out, int out_size, void* d_ws, size_t ws_size,
                              hipStream_t stream)
{
  (void)in_sizes; (void)n_in; (void)out_size; (void)ws_size;
  const float* node   = (const float*)d_in[0];
  const float* edge   = (const float*)d_in[1];
  const unsigned char* mask = (const unsigned char*)d_in[2];
  const float* qkv_w  = (const float*)d_in[3];
  const float* proj_w = (const float*)d_in[4];
  const float* proj_b = (const float*)d_in[5];
  const float* rw     = (const float*)d_in[6];
  const float* rb     = (const float*)d_in[7];
  const float* ew     = (const float*)d_in[8];
  const float* eb     = (const float*)d_in[9];
  const float* fcw    = (const float*)d_in[10];
  const float* fcb    = (const float*)d_in[11];

  float* out_node = (float*)d_out;
  float* out_edge = out_node + (size_t)16*256*512;

  char* ws = (char*)d_ws;
  unsigned short* qb  = (unsigned short*)(ws);                    // 4 MB
  uint2*          ktq = (uint2*)         (ws + (size_t)4*1024*1024);
  uint2*          vq  = (uint2*)         (ws + (size_t)8*1024*1024);
  unsigned short* tmpb= (unsigned short*)(ws + (size_t)12*1024*1024);

  qkv_gemm <<<dim3(32, 24, 1), 256, 0, stream>>>(node, qkv_w, qb, ktq, vq);
  fused_attn<<<dim3(1024, 1, 1), 256, 0, stream>>>(qb, ktq, vq, edge, mask,
                                                   rw, rb, ew, eb, fcw, fcb,
                                                   out_edge, tmpb);
  proj_gemm<<<dim3(32, 8, 1), 256, 0, stream>>>(tmpb, proj_w, proj_b, out_node);
}

// Round 15
// 184.409 us; speedup vs baseline: 2.5712x; 1.0617x over previous
//
#include <hip/hip_runtime.h>
#include <hip/hip_bf16.h>
#include <cstdint>
#include <cstddef>

#define SCALE_ 0.125f
// B=16 N=256 C=512 H=8 HD=64 E=64

typedef float f4_ __attribute__((ext_vector_type(4)));
typedef __bf16 bf2_ __attribute__((ext_vector_type(2)));
typedef short bf8f_ __attribute__((ext_vector_type(8)));   // MFMA A/B frag (8 bf16)
typedef float f32x4_ __attribute__((ext_vector_type(4)));  // MFMA C/D frag

__device__ __forceinline__ unsigned pk2(float a, float b) {
  union { __hip_bfloat16 h[2]; unsigned u; } x;
  x.h[0] = __float2bfloat16(a);
  x.h[1] = __float2bfloat16(b);
  return x.u;
}
__device__ __forceinline__ unsigned short bf16b(float a) {
  union { __hip_bfloat16 h; unsigned short s; } x;
  x.h = __float2bfloat16(a);
  return x.s;
}
__device__ __forceinline__ float blo(unsigned u) { return __uint_as_float(u << 16); }
__device__ __forceinline__ float bhi(unsigned u) { return __uint_as_float(u & 0xffff0000u); }
__device__ __forceinline__ float b2f(unsigned short s) { return __uint_as_float(((unsigned)s) << 16); }

// packed bf16 pair dot: d = a.lo*b.lo + a.hi*b.hi + c  (one VALU op on gfx950)
__device__ __forceinline__ float dot2b(unsigned a, unsigned b, float c) {
#if __has_builtin(__builtin_amdgcn_fdot2_f32_bf16)
  return __builtin_amdgcn_fdot2_f32_bf16(__builtin_bit_cast(bf2_, a),
                                         __builtin_bit_cast(bf2_, b), c, false);
#else
  return fmaf(blo(a), blo(b), fmaf(bhi(a), bhi(b), c));
#endif
}

template<int CTRL, int RM>
__device__ __forceinline__ float dppadd(float v) {
  int x = __builtin_amdgcn_update_dpp(0, __float_as_int(v), CTRL, RM, 0xf, true);
  return v + __int_as_float(x);
}
__device__ __forceinline__ float wave_sum64(float v) {
  v = dppadd<0x111, 0xf>(v);   // row_shr:1
  v = dppadd<0x112, 0xf>(v);   // row_shr:2
  v = dppadd<0x114, 0xf>(v);   // row_shr:4
  v = dppadd<0x118, 0xf>(v);   // row_shr:8
  v = dppadd<0x142, 0xa>(v);   // row_bcast:15 -> rows 1,3
  v = dppadd<0x143, 0xc>(v);   // row_bcast:31 -> rows 2,3
  return __int_as_float(__builtin_amdgcn_readlane(__float_as_int(v), 63));
}

// ------- Kernel 1: QKV projection GEMM via MFMA (bf16, f32 in, bf16 out) ----
__global__ __launch_bounds__(256) void qkv_gemm(
    const float* __restrict__ X, const float* __restrict__ W,
    unsigned short* __restrict__ qb, uint2* __restrict__ ktq, uint2* __restrict__ vq)
{
  __shared__ alignas(16) unsigned ABbuf[128*36 + 64*36];   // A | B, 27 KB
  unsigned* A_pk = ABbuf;                  // [128 rows][36 uints] (72 bf16)
  unsigned* B_pk = ABbuf + 128*36;         // [64 cols][36 uints]
  unsigned short* A16 = (unsigned short*)A_pk;
  unsigned short* B16 = (unsigned short*)B_pk;
  unsigned short* C16 = (unsigned short*)ABbuf;  // reuse: [128][68] bf16

  const int t  = threadIdx.x;
  const int lane = t & 63;
  const int wv = t >> 6;
  const int m0 = blockIdx.x * 128;
  const int o0 = blockIdx.y * 64;
  const int wrow = wv * 32;

  f32x4_ acc[2][4];
  #pragma unroll
  for (int fm = 0; fm < 2; fm++)
    #pragma unroll
    for (int fn = 0; fn < 4; fn++) acc[fm][fn] = (f32x4_){0.f, 0.f, 0.f, 0.f};

  const float4* X4 = (const float4*)X;
  const float4* W4 = (const float4*)W;

  for (int cc = 0; cc < 512; cc += 64) {
    #pragma unroll
    for (int i = 0; i < 8; i++) {
      int id = t + 256*i;
      int row = id >> 4, c4 = id & 15;
      float4 a = X4[(size_t)(m0 + row)*128 + (cc >> 2) + c4];
      A_pk[row*36 + c4*2    ] = pk2(a.x, a.y);
      A_pk[row*36 + c4*2 + 1] = pk2(a.z, a.w);
    }
    #pragma unroll
    for (int i = 0; i < 4; i++) {
      int id = t + 256*i;
      int row = id >> 4, c4 = id & 15;
      float4 w = W4[(size_t)(o0 + row)*128 + (cc >> 2) + c4];
      B_pk[row*36 + c4*2    ] = pk2(w.x, w.y);
      B_pk[row*36 + c4*2 + 1] = pk2(w.z, w.w);
    }
    __syncthreads();
    #pragma unroll
    for (int ks = 0; ks < 64; ks += 32) {
      const int kb = ks + (lane >> 4)*8;
      bf8f_ af0 = *(const bf8f_*)&A16[(wrow      + (lane & 15))*72 + kb];
      bf8f_ af1 = *(const bf8f_*)&A16[(wrow + 16 + (lane & 15))*72 + kb];
      #pragma unroll
      for (int fn = 0; fn < 4; fn++) {
        bf8f_ bf = *(const bf8f_*)&B16[(fn*16 + (lane & 15))*72 + kb];
        acc[0][fn] = __builtin_amdgcn_mfma_f32_16x16x32_bf16(af0, bf, acc[0][fn], 0, 0, 0);
        acc[1][fn] = __builtin_amdgcn_mfma_f32_16x16x32_bf16(af1, bf, acc[1][fn], 0, 0, 0);
      }
    }
    __syncthreads();
  }

  #pragma unroll
  for (int fm = 0; fm < 2; fm++)
    #pragma unroll
    for (int fn = 0; fn < 4; fn++)
      #pragma unroll
      for (int r = 0; r < 4; r++)
        C16[(wrow + fm*16 + (lane >> 4)*4 + r)*68 + fn*16 + (lane & 15)] =
          bf16b(acc[fm][fn][r]);
  __syncthreads();

  const int tm = (t & 15) * 8;
  const int to = (t >> 4) * 4;
  const int three = o0 >> 9;
  const int h = (o0 >> 6) & 7;
  if (three == 0) {
    #pragma unroll
    for (int i = 0; i < 8; i++) {
      int m = m0 + tm + i;
      int b = m >> 8, n = m & 255;
      uint2 u = *(const uint2*)&C16[(tm + i)*68 + to];
      *(uint2*)&qb[((size_t)(b*8 + h)*256 + n)*64 + to] = u;
    }
  } else if (three == 1) {
    #pragma unroll
    for (int i = 0; i < 8; i++) {
      int m = m0 + tm + i;
      int b = m >> 8, n = m & 255;
      uint2 u = *(const uint2*)&C16[(tm + i)*68 + to];
      ktq[(size_t)(b*8 + h)*4096 + (size_t)(to >> 2)*256 + n] = u;
    }
  } else {
    int m = m0 + tm;
    int b = m >> 8, n0 = m & 255;
    #pragma unroll
    for (int ii = 0; ii < 2; ii++) {
      #pragma unroll
      for (int j = 0; j < 4; j++) {
        unsigned ua = C16[(tm + 4*ii    )*68 + to + j];
        unsigned ub = C16[(tm + 4*ii + 1)*68 + to + j];
        unsigned uc = C16[(tm + 4*ii + 2)*68 + to + j];
        unsigned ud = C16[(tm + 4*ii + 3)*68 + to + j];
        vq[(size_t)(b*8 + h)*4096 + (size_t)((n0 >> 2) + ii)*64 + to + j] =
          make_uint2(ua | (ub << 16), uc | (ud << 16));
      }
    }
  }
}

// -------- Kernel 2: fused attn + edge pipeline (4 rows/block, 256t) ---------
// Phase 2 merged: edge-bias HBM stream interleaved with QK^T (L2+VALU) so the
// scheduler can overlap them — static unroll keeps all acc indices compile-time.
__global__ __launch_bounds__(256) void fused_attn(
    const unsigned short* __restrict__ qb, const uint2* __restrict__ ktq,
    const uint2* __restrict__ vq,
    const float* __restrict__ edge, const unsigned char* __restrict__ mask,
    const float* __restrict__ rw, const float* __restrict__ rb,
    const float* __restrict__ ew, const float* __restrict__ eb,
    const float* __restrict__ fcw, const float* __restrict__ fcb,
    float* __restrict__ out_edge, unsigned short* __restrict__ tmpb)
{
  __shared__ alignas(16) unsigned q_pk[4][8][32];      // 4 KB packed q (d-pairs)
  __shared__ alignas(16) unsigned char pt_raw[16896];  // p (bf16) then t8 (h-pairs)
  __shared__ alignas(16) unsigned short nacc16[4][512];// 4 KB PV result (bf16)
  __shared__ alignas(16) unsigned rw_pk[32][8];        // 1 KB rw e-pairs [ep][h]
  __shared__ alignas(16) unsigned ew_pk[64][4];        // 1 KB ew h-pairs [e][hp]
  __shared__ alignas(16) float eb_s[64];
  __shared__ alignas(16) float pl2[4][64];             // 1 KB
  __shared__ alignas(16) float inv_s[4][8];            // 1/sum

  unsigned short (*p_sb)[8][264] = (unsigned short (*)[8][264])pt_raw; // [r][h][y]
  unsigned (*t8_pk)[4][264] = (unsigned (*)[4][264])pt_raw;            // [r][hp][y]

  const int t = threadIdx.x;
  const int lane = t & 63;
  const int wv = t >> 6;
  const int b = blockIdx.x >> 6;
  const int x0 = (blockIdx.x & 63) * 4;
  const int y = t;

  // ---- phase 1: stage q packed (4 rows), rw/ew pairs, eb, mask
  #pragma unroll
  for (int i = 0; i < 4; i++) {
    int id = t + i*256;                 // 1024 uints
    int r = id >> 8, rest = id & 255;
    int h = rest >> 5, d2 = rest & 31;
    q_pk[r][h][d2] =
      *(const unsigned*)&qb[((size_t)(b*8 + h)*256 + x0 + r)*64 + d2*2];
  }
  { int epx = t >> 3, h = t & 7;
    rw_pk[epx][h] = pk2(rw[h*64 + 2*epx], rw[h*64 + 2*epx + 1]); }
  { int e = t >> 2, hp = t & 3;
    ew_pk[e][hp] = pk2(ew[(size_t)e*8 + 2*hp], ew[(size_t)e*8 + 2*hp + 1]); }
  if (t < 64) eb_s[t] = eb[t];
  float madd[4];
  #pragma unroll
  for (int r = 0; r < 4; r++)
    madd[r] = mask[(size_t)b*65536 + (size_t)(x0 + r)*256 + y] ? -1e30f : 0.f;
  __syncthreads();

  // ---- phase 2 (merged): edge bias stream INTERLEAVED with QK^T
  float acc[4][8];
  #pragma unroll
  for (int h = 0; h < 8; h++) {
    float rv = rb[h];
    #pragma unroll
    for (int r = 0; r < 4; r++) acc[r][h] = rv;
  }
  {
    const float* ep = edge + (size_t)b*(64*65536) + (size_t)x0*256 + y;
    #pragma unroll
    for (int h = 0; h < 8; h++) {
      const uint2* kq = ktq + (size_t)(b*8 + h)*4096 + y;
      float qk[4] = {0.f, 0.f, 0.f, 0.f};
      #pragma unroll
      for (int i = 0; i < 4; i++) {
        const int e2 = h*4 + i;
        // bias step e2: 8 NT HBM loads + 32 dot2
        unsigned vp[4];
        #pragma unroll
        for (int r = 0; r < 4; r++) {
          float a = __builtin_nontemporal_load(ep + (size_t)(2*e2)*65536 + r*256);
          float c = __builtin_nontemporal_load(ep + (size_t)(2*e2+1)*65536 + r*256);
          vp[r] = pk2(a, c);
        }
        uint4 w0 = *(const uint4*)&rw_pk[e2][0];
        uint4 w1 = *(const uint4*)&rw_pk[e2][4];
        unsigned wh[8] = {w0.x,w0.y,w0.z,w0.w,w1.x,w1.y,w1.z,w1.w};
        #pragma unroll
        for (int r = 0; r < 4; r++)
          #pragma unroll
          for (int hh = 0; hh < 8; hh++)
            acc[r][hh] = dot2b(vp[r], wh[hh], acc[r][hh]);
        // QK quarter for this h: d4 = i*4..i*4+3 (L2 loads + 32 dot2)
        #pragma unroll
        for (int dd = 0; dd < 4; dd++) {
          const int d4 = i*4 + dd;
          uint2 k = kq[(size_t)d4*256];
          #pragma unroll
          for (int r = 0; r < 4; r++) {
            uint2 qa = *(const uint2*)&q_pk[r][h][d4*2];
            qk[r] = dot2b(k.x, qa.x, qk[r]);
            qk[r] = dot2b(k.y, qa.y, qk[r]);
          }
        }
      }
      #pragma unroll
      for (int r = 0; r < 4; r++) acc[r][h] += SCALE_ * qk[r];
    }
  }

  // ---- phase 3: p = exp(s + mask) -> bf16 LDS
  #pragma unroll
  for (int r = 0; r < 4; r++)
    #pragma unroll
    for (int h = 0; h < 8; h++)
      p_sb[r][h][y] = bf16b(__expf(acc[r][h] + madd[r]));
  __syncthreads();

  // ---- phase 4: PV via dot2; v loads shared across 4 rows
  {
    const int h = t >> 5;
    const int i2 = t & 31;
    const int d0 = i2 * 2;
    const unsigned ONES = 0x3F803F80u;   // bf16 {1.0, 1.0}
    const uint4* vp4 = (const uint4*)(vq + (size_t)(b*8 + h)*4096);
    float a[4][2], ps[4];
    #pragma unroll
    for (int r = 0; r < 4; r++) { a[r][0] = 0.f; a[r][1] = 0.f; ps[r] = 0.f; }
    #pragma unroll 2
    for (int y4 = 0; y4 < 64; y4++) {
      uint4 u = vp4[(size_t)y4*32 + i2];
      #pragma unroll
      for (int r = 0; r < 4; r++) {
        uint2 pp = *(const uint2*)&p_sb[r][h][y4*4];
        a[r][0] = dot2b(pp.x, u.x, a[r][0]); a[r][0] = dot2b(pp.y, u.y, a[r][0]);
        a[r][1] = dot2b(pp.x, u.z, a[r][1]); a[r][1] = dot2b(pp.y, u.w, a[r][1]);
        ps[r] = dot2b(pp.x, ONES, ps[r]);    ps[r] = dot2b(pp.y, ONES, ps[r]);
      }
    }
    #pragma unroll
    for (int r = 0; r < 4; r++) {
      float inv = 1.0f / ps[r];
      *(unsigned*)&nacc16[r][h*64 + d0] = pk2(a[r][0]*inv, a[r][1]*inv);
      if (i2 == 0) inv_s[r][h] = inv;
    }
  }
  __syncthreads();   // p_sb fully consumed; nacc + inv ready

  // ---- phase 4.5: t8 = attn_sm + residual -> packed h-pairs (aliases p_sb)
  #pragma unroll
  for (int r = 0; r < 4; r++) {
    float v[8];
    #pragma unroll
    for (int h = 0; h < 8; h++)
      v[h] = __expf(acc[r][h] + madd[r]) * inv_s[r][h] + acc[r][h];
    t8_pk[r][0][y] = pk2(v[0], v[1]);
    t8_pk[r][1][y] = pk2(v[2], v[3]);
    t8_pk[r][2][y] = pk2(v[4], v[5]);
    t8_pk[r][3][y] = pk2(v[6], v[7]);
  }
  __syncthreads();

  // ---- phase 5: expand via dot2 + NT edge_out write + DPP pooling
  {
    const int r = wv;
    const int y0 = lane * 4;
    const int xg = x0 + r;
    uint4 tfq[4];
    #pragma unroll
    for (int hp = 0; hp < 4; hp++) tfq[hp] = *(const uint4*)&t8_pk[r][hp][y0];
    uchar4 mb = *(const uchar4*)&mask[(size_t)b*65536 + (size_t)xg*256 + y0];
    const float md0 = mb.x ? -1e30f : 0.f;
    const float md1 = mb.y ? -1e30f : 0.f;
    const float md2 = mb.z ? -1e30f : 0.f;
    const float md3 = mb.w ? -1e30f : 0.f;
    for (int e = 0; e < 64; e++) {
      uint4 w = *(const uint4*)&ew_pk[e][0];
      float ebv = eb_s[e];
      float eo0 = dot2b(tfq[3].x, w.w, dot2b(tfq[2].x, w.z,
                  dot2b(tfq[1].x, w.y, dot2b(tfq[0].x, w.x, ebv))));
      float eo1 = dot2b(tfq[3].y, w.w, dot2b(tfq[2].y, w.z,
                  dot2b(tfq[1].y, w.y, dot2b(tfq[0].y, w.x, ebv))));
      float eo2 = dot2b(tfq[3].z, w.w, dot2b(tfq[2].z, w.z,
                  dot2b(tfq[1].z, w.y, dot2b(tfq[0].z, w.x, ebv))));
      float eo3 = dot2b(tfq[3].w, w.w, dot2b(tfq[2].w, w.z,
                  dot2b(tfq[1].w, w.y, dot2b(tfq[0].w, w.x, ebv))));
      float e0v = __expf(eo0+md0), e1v = __expf(eo1+md1);
      float e2v = __expf(eo2+md2), e3v = __expf(eo3+md3);
      float se  = (e0v + e1v) + (e2v + e3v);
      float swe = (e0v*eo0 + e1v*eo1) + (e2v*eo2 + e3v*eo3);
      se  = wave_sum64(se);
      swe = wave_sum64(swe);
      if (lane == 0) pl2[r][e] = swe / se;
      f4_ ov = {eo0, eo1, eo2, eo3};
      __builtin_nontemporal_store(ov,
        (f4_*)&out_edge[((size_t)(b*64 + e)*256 + xg)*256 + y0]);
    }
  }
  __syncthreads();

  // ---- phase 6: node_tmp = PV + pool @ fc_w^T + fc_b (fw shared x4 rows)
  #pragma unroll
  for (int pass = 0; pass < 2; pass++) {
    int cdx = t + pass*256;
    float bias_c = fcb[cdx];
    float a[4];
    #pragma unroll
    for (int r = 0; r < 4; r++) a[r] = b2f(nacc16[r][cdx]) + bias_c;
    const float4* fw4 = (const float4*)fcw;
    #pragma unroll 4
    for (int e4 = 0; e4 < 16; e4++) {
      float4 f = fw4[(size_t)cdx*16 + e4];
      #pragma unroll
      for (int r = 0; r < 4; r++) {
        float4 pl = *(const float4*)&pl2[r][e4*4];
        a[r] += pl.x*f.x + pl.y*f.y + pl.z*f.z + pl.w*f.w;
      }
    }
    #pragma unroll
    for (int r = 0; r < 4; r++)
      tmpb[((size_t)b*256 + x0 + r)*512 + cdx] = bf16b(a[r]);
  }
}

// ------- Kernel 3: output projection GEMM + bias (bf16 dot2, bf16 in) -------
__global__ __launch_bounds__(256) void proj_gemm(
    const unsigned short* __restrict__ Xb, const float* __restrict__ W,
    const float* __restrict__ bias, float* __restrict__ out)
{
  __shared__ alignas(16) unsigned A_pk[8][132];   // [kpair][row] packed bf16
  __shared__ alignas(16) unsigned W_pk[8][68];    // [kpair][col]
  const int t  = threadIdx.x;
  const int m0 = blockIdx.x * 128;
  const int o0 = blockIdx.y * 64;
  const int tm = (t & 15) * 8;
  const int to = (t >> 4) * 4;
  float acc[8][4];
  #pragma unroll
  for (int i = 0; i < 8; i++)
    #pragma unroll
    for (int j = 0; j < 4; j++) acc[i][j] = 0.f;

  const uint4* X4 = (const uint4*)Xb;   // row = 64 uint4 (512 bf16, c-pairs)
  const float4* W4 = (const float4*)W;
  for (int c0 = 0; c0 < 512; c0 += 16) {
    {
      int row = t >> 1, half = t & 1;   // uint4 = 8 bf16 = 4 c-pairs
      uint4 a = X4[(size_t)(m0 + row) * 64 + (c0 >> 3) + half];
      A_pk[half*4 + 0][row] = a.x;
      A_pk[half*4 + 1][row] = a.y;
      A_pk[half*4 + 2][row] = a.z;
      A_pk[half*4 + 3][row] = a.w;
    }
    {
      int row = t >> 2, quad = t & 3;
      float4 w = W4[(size_t)(o0 + row) * 128 + (c0 >> 2) + quad];
      W_pk[quad*2    ][row] = pk2(w.x, w.y);
      W_pk[quad*2 + 1][row] = pk2(w.z, w.w);
    }
    __syncthreads();
    #pragma unroll
    for (int kp = 0; kp < 8; kp++) {
      uint4 a0 = *(const uint4*)&A_pk[kp][tm];
      uint4 a1 = *(const uint4*)&A_pk[kp][tm + 4];
      uint4 w0 = *(const uint4*)&W_pk[kp][to];
      unsigned am[8] = {a0.x,a0.y,a0.z,a0.w,a1.x,a1.y,a1.z,a1.w};
      unsigned wn[4] = {w0.x,w0.y,w0.z,w0.w};
      #pragma unroll
      for (int i = 0; i < 8; i++)
        #pragma unroll
        for (int j = 0; j < 4; j++) acc[i][j] = dot2b(am[i], wn[j], acc[i][j]);
    }
    __syncthreads();
  }
  float4 bb = *(const float4*)&bias[o0 + to];
  #pragma unroll
  for (int i = 0; i < 8; i++) {
    int m = m0 + tm + i;
    float4 r = make_float4(acc[i][0]+bb.x, acc[i][1]+bb.y, acc[i][2]+bb.z, acc[i][3]+bb.w);
    *(float4*)&out[(size_t)m*512 + o0 + to] = r;
  }
}

extern "C" void kernel_launch(void* const* d_in, const int* in_sizes, int n_in,
                              void* d_out, int out_size, void* d_ws, size_t ws_size,
                              hipStream_t stream)
{
  (void)in_sizes; (void)n_in; (void)out_size; (void)ws_size;
  const float* node   = (const float*)d_in[0];
  const float* edge   = (const float*)d_in[1];
  const unsigned char* mask = (const unsigned char*)d_in[2];
  const float* qkv_w  = (const float*)d_in[3];
  const float* proj_w = (const float*)d_in[4];
  const float* proj_b = (const float*)d_in[5];
  const float* rw     = (const float*)d_in[6];
  const float* rb     = (const float*)d_in[7];
  const float* ew     = (const float*)d_in[8];
  const float* eb     = (const float*)d_in[9];
  const float* fcw    = (const float*)d_in[10];
  const float* fcb    = (const float*)d_in[11];

  float* out_node = (float*)d_out;
  float* out_edge = out_node + (size_t)16*256*512;

  char* ws = (char*)d_ws;
  unsigned short* qb  = (unsigned short*)(ws);                    // 4 MB
  uint2*          ktq = (uint2*)         (ws + (size_t)4*1024*1024);
  uint2*          vq  = (uint2*)         (ws + (size_t)8*1024*1024);
  unsigned short* tmpb= (unsigned short*)(ws + (size_t)12*1024*1024);

  qkv_gemm <<<dim3(32, 24, 1), 256, 0, stream>>>(node, qkv_w, qb, ktq, vq);
  fused_attn<<<dim3(1024, 1, 1), 256, 0, stream>>>(qb, ktq, vq, edge, mask,
                                                   rw, rb, ew, eb, fcw, fcb,
                                                   out_edge, tmpb);
  proj_gemm<<<dim3(32, 8, 1), 256, 0, stream>>>(tmpb, proj_w, proj_b, out_node);
}